// Round 15
// baseline (1057.659 us; speedup 1.0000x reference)
//
#include <hip/hip_runtime.h>
#include <hip/hip_bf16.h>

typedef __attribute__((ext_vector_type(8))) short short8;
typedef __attribute__((ext_vector_type(4))) float f32x4;
typedef __hip_bfloat16 bf16;

__device__ __forceinline__ short f2bs_rn(float f) {   // fast RNE bf16 pack
    unsigned u = __builtin_bit_cast(unsigned, f);
    u += 0x7FFF + ((u >> 16) & 1);
    return (short)(u >> 16);
}
__device__ __forceinline__ float bs2f(short s) {
    unsigned u = ((unsigned)(unsigned short)s) << 16;
    return __builtin_bit_cast(float, u);
}
__device__ __forceinline__ float ldf(const void* p, int i, int flag) {
    return flag ? bs2f(((const short*)p)[i]) : ((const float*)p)[i];
}
__device__ __forceinline__ short ldbits(const void* p, int i, int flag) {
    return flag ? ((const short*)p)[i] : f2bs_rn(((const float*)p)[i]);
}
__device__ __forceinline__ void stf(void* p, int i, float v, int flag) {
    if (flag) ((bf16*)p)[i] = __float2bfloat16(v);
    else ((float*)p)[i] = v;
}
__device__ __forceinline__ float nz(float v) { return (v == v) ? v : 0.f; }
__device__ __forceinline__ float siluf(float v) {
    return v * __builtin_amdgcn_rcpf(1.f + __expf(-v));
}
__device__ __forceinline__ float sigmf(float v) {
    return __builtin_amdgcn_rcpf(1.f + __expf(-v));
}

// ---------------------------------------------------------------------------
__global__ void detect_kernel(const unsigned int* __restrict__ hw, int* __restrict__ flag) {
    unsigned int w = hw[threadIdx.x];
    unsigned int e = (w >> 7) & 0xFF;
    bool ok = (e >= 113 && e <= 135);
    unsigned long long m = __ballot(ok);
    if (threadIdx.x == 0) *flag = (__popcll(m) >= 32) ? 1 : 0;
}

// ---------------------------------------------------------------------------
// prep: ALL weights in MFMA B-fragment order:
//   frag chunk c = kc*NT + nt, element r = lane*8 + j
//   -> W[k = kc*32 + (lane>>4)*8 + j][n = nt*16 + (lane&15)]
// biasblk extended with W1 rows 256 (dist) / 257 (attr) at 1156 / 1284.
// ---------------------------------------------------------------------------
__global__ void prep_kernel(
    const void* eW1, const void* eW2, const void* cW1, const void* iW1,
    const void* eb1, const void* eb2, const void* cb1, const void* cw2,
    const void* ib1, const void* iw2, const void* ib2, const void* nb1,
    const void* nb2, const void* vb1, const void* vW2,
    const void* nW1, const void* nW2, const void* vW1,
    short* __restrict__ W1t, short* __restrict__ W2t,
    short* __restrict__ cW1t, short* __restrict__ iW1t,
    float* __restrict__ biasblk, short* __restrict__ nW1b,
    short* __restrict__ nW2b, short* __restrict__ vW1b,
    const int* __restrict__ flagp) {
    const int flag = *flagp;
    int i = blockIdx.x * 256 + threadIdx.x;
    if (i < 36864) {  // W1 fragments: 9 kc x 8 nt x 512
        int c = i >> 9, r = i & 511;
        int kc = c >> 3, nt = c & 7;
        int ln = r >> 3, j = r & 7;
        int k = kc * 32 + ((ln >> 4) << 3) + j;
        int n = nt * 16 + (ln & 15);
        W1t[i] = (k < 258) ? ldbits(eW1, k * 128 + n, flag) : (short)0;
        return;
    }
    i -= 36864;
    if (i < 16384) {  // W2 fragments: 4 kc x 8 nt
        int c = i >> 9, r = i & 511;
        int kc = c >> 3, nt = c & 7;
        int ln = r >> 3, j = r & 7;
        int k = kc * 32 + ((ln >> 4) << 3) + j;
        int n = nt * 16 + (ln & 15);
        W2t[i] = ldbits(eW2, k * 128 + n, flag);
        return;
    }
    i -= 16384;
    if (i < 16384) {  // coord W1 fragments: 4 kc x 8 nt
        int c = i >> 9, r = i & 511;
        int kc = c >> 3, nt = c & 7;
        int ln = r >> 3, j = r & 7;
        int k = kc * 32 + ((ln >> 4) << 3) + j;
        int n = nt * 16 + (ln & 15);
        cW1t[i] = ldbits(cW1, k * 128 + n, flag);
        return;
    }
    i -= 16384;
    if (i < 8192) {  // inf W1 fragments: 4 kc x 4 nt
        int c = i >> 9, r = i & 511;
        int kc = c >> 2, nt = c & 3;
        int ln = r >> 3, j = r & 7;
        int k = kc * 32 + ((ln >> 4) << 3) + j;
        int n = nt * 16 + (ln & 15);
        iW1t[i] = ldbits(iW1, k * 64 + n, flag);
        return;
    }
    i -= 8192;
    if (i < 1412) {
        float v;
        if (i < 128) v = ldf(eb1, i, flag);
        else if (i < 256) v = ldf(eb2, i - 128, flag);
        else if (i < 384) v = ldf(cb1, i - 256, flag);
        else if (i < 512) v = ldf(cw2, i - 384, flag);
        else if (i < 576) v = ldf(ib1, i - 512, flag);
        else if (i < 640) v = ldf(iw2, i - 576, flag);
        else if (i < 644) v = (i == 640) ? ldf(ib2, 0, flag) : 0.f;
        else if (i < 772) v = ldf(nb1, i - 644, flag);
        else if (i < 900) v = ldf(nb2, i - 772, flag);
        else if (i < 1028) v = ldf(vb1, i - 900, flag);
        else if (i < 1156) v = ldf(vW2, i - 1028, flag);
        else if (i < 1284) v = ldf(eW1, 256 * 128 + (i - 1156), flag);  // dist row
        else v = ldf(eW1, 257 * 128 + (i - 1284), flag);                // attr row
        biasblk[i] = v;
        return;
    }
    i -= 1412;
    if (i < 32768) {  // node W1 fragments: 8 kc x 8 nt
        int c = i >> 9, r = i & 511;
        int kc = c >> 3, nt = c & 7;
        int ln = r >> 3, j = r & 7;
        int k = kc * 32 + ((ln >> 4) << 3) + j;
        int n = nt * 16 + (ln & 15);
        nW1b[i] = ldbits(nW1, k * 128 + n, flag);
        return;
    }
    i -= 32768;
    if (i < 16384) {  // node W2 fragments: 4 kc x 8 nt
        int c = i >> 9, r = i & 511;
        int kc = c >> 3, nt = c & 7;
        int ln = r >> 3, j = r & 7;
        int k = kc * 32 + ((ln >> 4) << 3) + j;
        int n = nt * 16 + (ln & 15);
        nW2b[i] = ldbits(nW2, k * 128 + n, flag);
        return;
    }
    i -= 16384;
    if (i < 16384) {  // vel W1 fragments: 4 kc x 8 nt
        int c = i >> 9, r = i & 511;
        int kc = c >> 3, nt = c & 7;
        int ln = r >> 3, j = r & 7;
        int k = kc * 32 + ((ln >> 4) << 3) + j;
        int n = nt * 16 + (ln & 15);
        vW1b[i] = ldbits(vW1, k * 128 + n, flag);
    }
}

// ---------------------------------------------------------------------------
// convh + count fused: one launch streams h->hb (N*128 elems) and counts
// edge rows (E elems). Independent data; saves a launch and overlaps.
// ---------------------------------------------------------------------------
__global__ void convh_count_kernel(const void* __restrict__ h, short* __restrict__ hb,
                                   const int* __restrict__ erow, int* __restrict__ cnt,
                                   const int* __restrict__ flagp, int n, int E) {
    const int flag = *flagp;
    int i = blockIdx.x * 256 + threadIdx.x;
    if (i < n) hb[i] = ldbits(h, i, flag);
    if (i < E) atomicAdd(&cnt[erow[i]], 1);
}

// ---------------------------------------------------------------------------
// hw1: precompute hA = h @ W1[0:128], hB = h @ W1[128:256] (bf16, N x 128).
// ---------------------------------------------------------------------------
__global__ __launch_bounds__(256) void hw1_kernel(
    const short* __restrict__ hb, const short* __restrict__ W1t,
    short* __restrict__ hA, short* __restrict__ hB, int N) {
    const int tid = threadIdx.x;
    const int wv = tid >> 6;
    const int lane = tid & 63;
    const int n15 = lane & 15;
    const int quad = lane >> 4;
    const int base = blockIdx.x * 128 + wv * 32;

    f32x4 accA[2][8], accB[2][8];
#pragma unroll
    for (int m = 0; m < 2; ++m)
#pragma unroll
        for (int nt = 0; nt < 8; ++nt) {
            accA[m][nt] = (f32x4){0.f, 0.f, 0.f, 0.f};
            accB[m][nt] = (f32x4){0.f, 0.f, 0.f, 0.f};
        }

#pragma unroll
    for (int kc = 0; kc < 4; ++kc) {
        short8 a[2];
#pragma unroll
        for (int m = 0; m < 2; ++m) {
            int node = base + m * 16 + n15;
            if (node >= N) node = N - 1;
            a[m] = *(const short8*)(hb + node * 128 + kc * 32 + quad * 8);
        }
        const short* bpA = W1t + (kc * 8) * 512 + lane * 8;
        const short* bpB = W1t + ((kc + 4) * 8) * 512 + lane * 8;
#pragma unroll
        for (int nt = 0; nt < 8; ++nt) {
            short8 ba = *(const short8*)(bpA + nt * 512);
            short8 bb = *(const short8*)(bpB + nt * 512);
            accA[0][nt] = __builtin_amdgcn_mfma_f32_16x16x32_bf16(a[0], ba, accA[0][nt], 0, 0, 0);
            accA[1][nt] = __builtin_amdgcn_mfma_f32_16x16x32_bf16(a[1], ba, accA[1][nt], 0, 0, 0);
            accB[0][nt] = __builtin_amdgcn_mfma_f32_16x16x32_bf16(a[0], bb, accB[0][nt], 0, 0, 0);
            accB[1][nt] = __builtin_amdgcn_mfma_f32_16x16x32_bf16(a[1], bb, accB[1][nt], 0, 0, 0);
        }
    }

#pragma unroll
    for (int m = 0; m < 2; ++m)
#pragma unroll
        for (int nt = 0; nt < 8; ++nt)
#pragma unroll
            for (int r = 0; r < 4; ++r) {
                int node = base + m * 16 + quad * 4 + r;
                if (node < N) {
                    hA[node * 128 + nt * 16 + n15] = f2bs_rn(accA[m][nt][r]);
                    hB[node * 128 + nt * 16 + n15] = f2bs_rn(accB[m][nt][r]);
                }
            }
}

// ---------------------------------------------------------------------------
// CSR build
// ---------------------------------------------------------------------------
__global__ __launch_bounds__(1024) void scan1_kernel(const int* __restrict__ cnt,
                                                     int* __restrict__ off,
                                                     int* __restrict__ bsum, int N) {
    __shared__ int sm[1024];
    int t = threadIdx.x, i = blockIdx.x * 1024 + t;
    int c = (i < N) ? cnt[i] : 0;
    sm[t] = c;
    __syncthreads();
    for (int d = 1; d < 1024; d <<= 1) {
        int v = (t >= d) ? sm[t - d] : 0;
        __syncthreads();
        sm[t] += v;
        __syncthreads();
    }
    if (i < N) off[i] = sm[t] - c;
    if (t == 1023) bsum[blockIdx.x] = sm[1023];
}
// parallel scan over block sums (nb <= 1024): single 1024-thread block
__global__ __launch_bounds__(1024) void scan2_kernel(const int* __restrict__ bsum,
                                                     int* __restrict__ bpre, int nb) {
    __shared__ int sm[1024];
    int t = threadIdx.x;
    int c = (t < nb) ? bsum[t] : 0;
    sm[t] = c;
    __syncthreads();
    for (int d = 1; d < 1024; d <<= 1) {
        int v = (t >= d) ? sm[t - d] : 0;
        __syncthreads();
        sm[t] += v;
        __syncthreads();
    }
    if (t < nb) bpre[t] = sm[t] - c;   // exclusive prefix of block sums
}
__global__ void scan3_kernel(int* __restrict__ off, const int* __restrict__ bpre, int N) {
    int i = blockIdx.x * 256 + threadIdx.x;
    if (i < N) off[i] += bpre[i >> 10];
}
__global__ void fill_kernel(const int* __restrict__ erow, const int* __restrict__ off,
                            int* __restrict__ cur, int* __restrict__ elist, int E) {
    int i = blockIdx.x * 256 + threadIdx.x;
    if (i < E) {
        int r = erow[i];
        int p = off[r] + atomicAdd(&cur[r], 1);
        elist[p] = i;
    }
}

// ---------------------------------------------------------------------------
// edge kernel (PRE path): 4 waves x 16 edges, one m-tile per wave.
// (256,5) is the occupancy-sweep optimum (4blk=573us, 5blk=535us, 6blk=632us).
// hidden1 in registers; XCD swizzle; merged segment reduction.
// UNCHANGED from the round-13 measured winner.
// ---------------------------------------------------------------------------
template <bool CSR>
__global__ __launch_bounds__(256, 5) void edge_kernel(
    const short* __restrict__ hA, const short* __restrict__ hB,
    const void* __restrict__ x, const void* __restrict__ eattr,
    const int* __restrict__ erow, const int* __restrict__ ecol,
    const int* __restrict__ elist,
    const short* __restrict__ W2f, const short* __restrict__ cW1f,
    const short* __restrict__ iW1f,
    const float* __restrict__ biasblk,
    float* __restrict__ m_i, float* __restrict__ agg_x, int E,
    const int* __restrict__ flagp) {
    const int flag = *flagp;
    __shared__ __align__(16) short tiles[4][16 * 136];  // 17408 B
    const float* b1f = biasblk;
    const float* b2f = biasblk + 128;
    const float* cb1f = biasblk + 256;
    const float* cw2f = biasblk + 384;
    const float* ib1f = biasblk + 512;
    const float* iw2f = biasblk + 576;
    const float ib2s = biasblk[640];
    const float* w1df = biasblk + 1156;
    const float* w1af = biasblk + 1284;

    // bijective chunked XCD swizzle (m204): consecutive CSR tiles -> same XCD.
    int bid;
    {
        const int nwg = gridDim.x;
        const int qq = nwg >> 3, r8 = nwg & 7;
        const int xcd = blockIdx.x & 7, idx = blockIdx.x >> 3;
        const int base = (xcd < r8) ? xcd * (qq + 1) : r8 * (qq + 1) + (xcd - r8) * qq;
        bid = base + idx;
    }

    const int tid = threadIdx.x;
    const int wv = tid >> 6;
    const int lane = tid & 63;
    const int n15 = lane & 15;
    const int quad = lane >> 4;
    const int wb = bid * 64 + wv * 16;

    int row_e, col_e;
    float dist, attr;
    {
        int slot = wb + n15;
        int sL = (slot < E) ? slot : (E - 1);
        int eL = CSR ? elist[sL] : sL;
        row_e = erow[eL];
        col_e = ecol[eL];
        float d = 0.f;
#pragma unroll
        for (int dd = 0; dd < 3; ++dd) {
            float xd = ldf(x, row_e * 3 + dd, flag) - ldf(x, col_e * 3 + dd, flag);
            d += xd * xd;
        }
        dist = d;
        attr = ldf(eattr, eL, flag);
    }

    // ---- col partial gather (random, L3 latency): 16 VGPR
    short8 cB[4];
#pragma unroll
    for (int c = 0; c < 4; ++c)
        cB[c] = *(const short8*)(hB + col_e * 128 + c * 32 + quad * 8);

    // ---- m1 = hA[row] + hB[col] + dist*W1d + attr*W1at + b1 -> silu
    // kept in REGISTERS: combine layout == GEMM2 A-fragment layout.
    short* tl = tiles[wv];
    short8 h1[4];
#pragma unroll
    for (int c = 0; c < 4; ++c) {
        short8 ra = *(const short8*)(hA + row_e * 128 + c * 32 + quad * 8);
        short8 ov;
#pragma unroll
        for (int j = 0; j < 8; ++j) {
            int f = c * 32 + quad * 8 + j;
            float v = bs2f(ra[j]) + bs2f(cB[c][j])
                    + dist * w1df[f] + attr * w1af[f] + b1f[f];
            ov[j] = f2bs_rn(siluf(v));
        }
        h1[c] = ov;
    }

    // ---- GEMM2: hidden1 @ W2 (A straight from registers)
    f32x4 acc2[8];
#pragma unroll
    for (int nt = 0; nt < 8; ++nt) acc2[nt] = (f32x4){0.f, 0.f, 0.f, 0.f};
#pragma unroll
    for (int kc = 0; kc < 4; ++kc) {
        short8 a = h1[kc];
        const short* bp = W2f + (kc * 8) * 512 + lane * 8;
#pragma unroll
        for (int nt = 0; nt < 8; ++nt) {
            short8 b = *(const short8*)(bp + nt * 512);
            acc2[nt] = __builtin_amdgcn_mfma_f32_16x16x32_bf16(a, b, acc2[nt], 0, 0, 0);
        }
    }

    // mv (bf16) -> LDS tile (C-layout transpose); needed by GEMM3/4 + m_i.
#pragma unroll
    for (int nt = 0; nt < 8; ++nt) {
        float bv = b2f[nt * 16 + n15];
#pragma unroll
        for (int r = 0; r < 4; ++r)
            tl[(quad * 4 + r) * 136 + nt * 16 + n15] = f2bs_rn(siluf(acc2[nt][r] + bv));
    }

    // ---- GEMM4 (inf, 64 cols) -> eij
    f32x4 acc4[4];
#pragma unroll
    for (int nt = 0; nt < 4; ++nt) acc4[nt] = (f32x4){0.f, 0.f, 0.f, 0.f};
#pragma unroll
    for (int kc = 0; kc < 4; ++kc) {
        short8 a = *(const short8*)(tl + n15 * 136 + kc * 32 + quad * 8);
        const short* bp = iW1f + (kc * 4) * 512 + lane * 8;
#pragma unroll
        for (int nt = 0; nt < 4; ++nt) {
            short8 b = *(const short8*)(bp + nt * 512);
            acc4[nt] = __builtin_amdgcn_mfma_f32_16x16x32_bf16(a, b, acc4[nt], 0, 0, 0);
        }
    }
    float eij[4];
    {
        float inp[4] = {0.f, 0.f, 0.f, 0.f};
#pragma unroll
        for (int nt = 0; nt < 4; ++nt) {
            float ib = ib1f[nt * 16 + n15];
            float iw = iw2f[nt * 16 + n15];
#pragma unroll
            for (int r = 0; r < 4; ++r) inp[r] += siluf(acc4[nt][r] + ib) * iw;
        }
#pragma unroll
        for (int mk = 1; mk < 16; mk <<= 1)
#pragma unroll
            for (int r = 0; r < 4; ++r) inp[r] += __shfl_xor(inp[r], mk);
#pragma unroll
        for (int r = 0; r < 4; ++r) eij[r] = sigmf(inp[r] + ib2s);
    }

    // ---- GEMM3 (coord) -> phi
    f32x4 acc3[8];
#pragma unroll
    for (int nt = 0; nt < 8; ++nt) acc3[nt] = (f32x4){0.f, 0.f, 0.f, 0.f};
#pragma unroll
    for (int kc = 0; kc < 4; ++kc) {
        short8 a = *(const short8*)(tl + n15 * 136 + kc * 32 + quad * 8);
        const short* bp = cW1f + (kc * 8) * 512 + lane * 8;
#pragma unroll
        for (int nt = 0; nt < 8; ++nt) {
            short8 b = *(const short8*)(bp + nt * 512);
            acc3[nt] = __builtin_amdgcn_mfma_f32_16x16x32_bf16(a, b, acc3[nt], 0, 0, 0);
        }
    }

    // ---- epilogue + aggregation
    {
        float php[4] = {0.f, 0.f, 0.f, 0.f};
#pragma unroll
        for (int nt = 0; nt < 8; ++nt) {
            float cb = cb1f[nt * 16 + n15];
            float cw = cw2f[nt * 16 + n15];
#pragma unroll
            for (int r = 0; r < 4; ++r) php[r] += siluf(acc3[nt][r] + cb) * cw;
        }
#pragma unroll
        for (int mk = 1; mk < 16; mk <<= 1)
#pragma unroll
            for (int r = 0; r < 4; ++r) php[r] += __shfl_xor(php[r], mk);
        // php[r]/eij[r] now uniform across n15 within each quad

        // distribute per-edge s = eij*php to the lane owning edge n15:
        // source quad = n15>>2, slot r = n15&3
        float sv[4];
#pragma unroll
        for (int r = 0; r < 4; ++r) sv[r] = eij[r] * php[r];
        const int srcl = (n15 >> 2) * 16;
        float t0 = __shfl(sv[0], srcl);
        float t1 = __shfl(sv[1], srcl);
        float t2 = __shfl(sv[2], srcl);
        float t3 = __shfl(sv[3], srcl);
        const int rr = n15 & 3;
        float s_e = (rr == 0) ? t0 : (rr == 1) ? t1 : (rr == 2) ? t2 : t3;

        // per-lane dim contribution: quad = dim (quad 3 idle)
        float val = 0.f;
        if (quad < 3) {
            float xd = ldf(x, row_e * 3 + quad, flag) - ldf(x, col_e * 3 + quad, flag);
            val = ((wb + n15) < E) ? nz(s_e * xd) : 0.f;
        }

        const int ebase = wb;
        if (CSR) {
            // merged segment loop: m_i (LDS mv) + agg_x, one atomic set per row
            int p = 0;
            while (p < 16 && (ebase + p) < E) {
                int rowp = __shfl(row_e, p);
                unsigned bal = (unsigned)__ballot(row_e == rowp) & 0xFFFFu;
                unsigned bits = (~bal) >> p;  // bit16 of ~bal is set -> bounded
                int q = p + __builtin_ctz(bits);

                // agg_x: sum val over n15 in [p,q) within each quad (dim)
                float av = (n15 >= p && n15 < q) ? val : 0.f;
#pragma unroll
                for (int mk = 1; mk < 16; mk <<= 1) av += __shfl_xor(av, mk);
                if (n15 == 0 && quad < 3) atomicAdd(&agg_x[rowp * 3 + quad], av);

                // m_i: weighted sum of LDS mv rows
                float s[8];
#pragma unroll
                for (int nt = 0; nt < 8; ++nt) s[nt] = 0.f;
#pragma unroll
                for (int r = 0; r < 4; ++r) {
                    int idx = quad * 4 + r;
                    bool in = (idx >= p) && (idx < q) && ((ebase + idx) < E);
                    float w = in ? eij[r] : 0.f;
#pragma unroll
                    for (int nt = 0; nt < 8; ++nt)
                        s[nt] += w * bs2f(tl[idx * 136 + nt * 16 + n15]);
                }
#pragma unroll
                for (int nt = 0; nt < 8; ++nt) {
                    s[nt] += __shfl_xor(s[nt], 16);
                    s[nt] += __shfl_xor(s[nt], 32);
                }
                if (quad == 0) {
#pragma unroll
                    for (int nt = 0; nt < 8; ++nt)
                        atomicAdd(&m_i[(size_t)rowp * 128 + nt * 16 + n15], nz(s[nt]));
                }
                p = q;
            }
        } else {
            // per-edge fallback (rows unsorted): lane-parallel agg_x
            if (quad < 3 && (wb + n15) < E)
                atomicAdd(&agg_x[row_e * 3 + quad], val);
#pragma unroll
            for (int nt = 0; nt < 8; ++nt)
#pragma unroll
                for (int r = 0; r < 4; ++r) {
                    int idx = quad * 4 + r;
                    if ((ebase + idx) < E) {
                        int er = __shfl(row_e, idx);
                        atomicAdd(&m_i[er * 128 + nt * 16 + n15],
                                  nz(eij[r] * bs2f(tl[idx * 136 + nt * 16 + n15])));
                    }
                }
        }
    }
}

// ---------------------------------------------------------------------------
// node kernel (MFMA): round-9 proven version, unchanged.
// ---------------------------------------------------------------------------
__global__ __launch_bounds__(256, 4) void node_kernel(
    const short* __restrict__ hb, const void* __restrict__ x,
    const void* __restrict__ v_init,
    const int* __restrict__ cnt,
    const float* __restrict__ m_i, const float* __restrict__ agg_x,
    const short* __restrict__ nW1f, const short* __restrict__ nW2f,
    const short* __restrict__ vW1f, const float* __restrict__ biasblk,
    void* __restrict__ out, int N, int xbase, int vbase, float inv_nm1,
    const int* __restrict__ flagp) {
    const int flag = *flagp;
    __shared__ __align__(16) short tiles[4][16 * 136];  // 17408 B
    const float* nb1f = biasblk + 644;
    const float* nb2f = biasblk + 772;
    const float* vb1f = biasblk + 900;
    const float* vW2f = biasblk + 1028;

    const int tid = threadIdx.x;
    const int wv = tid >> 6;
    const int lane = tid & 63;
    const int n15 = lane & 15;
    const int quad = lane >> 4;
    const int base = blockIdx.x * 64 + wv * 16;

    short* tl = tiles[wv];

    // ---- stage m_i (bf16 + nz) into tile: row n15, col c*32+quad*8..+8
    {
        int node = base + n15;
        if (node >= N) node = N - 1;
#pragma unroll
        for (int c = 0; c < 4; ++c) {
            const float* mp = m_i + (size_t)node * 128 + c * 32 + quad * 8;
            short8 ov;
#pragma unroll
            for (int j = 0; j < 8; ++j) ov[j] = f2bs_rn(nz(mp[j]));
            *(short8*)(tl + n15 * 136 + c * 32 + quad * 8) = ov;
        }
    }
    int anode = base + n15;
    if (anode >= N) anode = N - 1;

    // ---- vel GEMM: h @ vW1 -> silu -> * vW2 -> row-reduce -> vscale
    f32x4 acc[8];
#pragma unroll
    for (int nt = 0; nt < 8; ++nt) acc[nt] = (f32x4){0.f, 0.f, 0.f, 0.f};
#pragma unroll
    for (int kc = 0; kc < 4; ++kc) {
        short8 a = *(const short8*)(hb + (size_t)anode * 128 + kc * 32 + quad * 8);
        const short* bp = vW1f + (kc * 8) * 512 + lane * 8;
#pragma unroll
        for (int nt = 0; nt < 8; ++nt) {
            short8 b = *(const short8*)(bp + nt * 512);
            acc[nt] = __builtin_amdgcn_mfma_f32_16x16x32_bf16(a, b, acc[nt], 0, 0, 0);
        }
    }
    float vsc[4] = {0.f, 0.f, 0.f, 0.f};
#pragma unroll
    for (int nt = 0; nt < 8; ++nt) {
        int j = nt * 16 + n15;
        float vb = vb1f[j];
        float vw = vW2f[j];
#pragma unroll
        for (int r = 0; r < 4; ++r) vsc[r] += siluf(acc[nt][r] + vb) * vw;
    }
#pragma unroll
    for (int mk = 1; mk < 16; mk <<= 1)
#pragma unroll
        for (int r = 0; r < 4; ++r) vsc[r] += __shfl_xor(vsc[r], mk);

    // ---- node GEMM1: [h | m_i] @ nW1 -> silu -> tile
#pragma unroll
    for (int nt = 0; nt < 8; ++nt) acc[nt] = (f32x4){0.f, 0.f, 0.f, 0.f};
#pragma unroll
    for (int kc = 0; kc < 8; ++kc) {
        short8 a;
        if (kc < 4) a = *(const short8*)(hb + (size_t)anode * 128 + kc * 32 + quad * 8);
        else        a = *(const short8*)(tl + n15 * 136 + (kc - 4) * 32 + quad * 8);
        const short* bp = nW1f + (kc * 8) * 512 + lane * 8;
#pragma unroll
        for (int nt = 0; nt < 8; ++nt) {
            short8 b = *(const short8*)(bp + nt * 512);
            acc[nt] = __builtin_amdgcn_mfma_f32_16x16x32_bf16(a, b, acc[nt], 0, 0, 0);
        }
    }
#pragma unroll
    for (int nt = 0; nt < 8; ++nt) {
        float bv = nb1f[nt * 16 + n15];
#pragma unroll
        for (int r = 0; r < 4; ++r)
            tl[(quad * 4 + r) * 136 + nt * 16 + n15] = f2bs_rn(siluf(acc[nt][r] + bv));
    }

    // ---- node GEMM2: hidden @ nW2 -> out
#pragma unroll
    for (int nt = 0; nt < 8; ++nt) acc[nt] = (f32x4){0.f, 0.f, 0.f, 0.f};
#pragma unroll
    for (int kc = 0; kc < 4; ++kc) {
        short8 a = *(const short8*)(tl + n15 * 136 + kc * 32 + quad * 8);
        const short* bp = nW2f + (kc * 8) * 512 + lane * 8;
#pragma unroll
        for (int nt = 0; nt < 8; ++nt) {
            short8 b = *(const short8*)(bp + nt * 512);
            acc[nt] = __builtin_amdgcn_mfma_f32_16x16x32_bf16(a, b, acc[nt], 0, 0, 0);
        }
    }
#pragma unroll
    for (int nt = 0; nt < 8; ++nt) {
        float bv = nb2f[nt * 16 + n15];
#pragma unroll
        for (int r = 0; r < 4; ++r) {
            int node = base + quad * 4 + r;
            if (node < N) stf(out, node * 128 + nt * 16 + n15, nz(acc[nt][r] + bv), flag);
        }
    }

    // ---- x / v outputs (3 dims per node; lanes n15<3 of each quad)
    if (n15 < 3) {
#pragma unroll
        for (int r = 0; r < 4; ++r) {
            int node = base + quad * 4 + r;
            if (node >= N) continue;
            int d = n15;
            float vj = nz(ldf(v_init, node * 3 + d, flag) * vsc[r]);
            stf(out, vbase + node * 3 + d, vj, flag);
            float xv = ldf(x, node * 3 + d, flag);
            float xo = (cnt[node] > 0) ? xv + vj + nz(agg_x[node * 3 + d]) * inv_nm1 : xv;
            stf(out, xbase + node * 3 + d, nz(xo), flag);
        }
    }
}

// ---------------------------------------------------------------------------
// legacy edge kernel (round-2 exact): used only when workspace too small.
// ---------------------------------------------------------------------------
template <bool CSR>
__global__ __launch_bounds__(256, 2) void edge_kernel_old(
    const short* __restrict__ hb, const void* __restrict__ x,
    const void* __restrict__ eattr,
    const int* __restrict__ erow, const int* __restrict__ ecol,
    const int* __restrict__ elist,
    const short* __restrict__ W1f, const short* __restrict__ W2f,
    const short* __restrict__ cW1f, const short* __restrict__ iW1f,
    const float* __restrict__ biasblk,
    float* __restrict__ m_i, float* __restrict__ agg_x, int E,
    const int* __restrict__ flagp) {
    const int flag = *flagp;
    __shared__ __align__(16) short tiles[8][16 * 136];
    const float* b1f = biasblk;
    const float* b2f = biasblk + 128;
    const float* cb1f = biasblk + 256;
    const float* cw2f = biasblk + 384;
    const float* ib1f = biasblk + 512;
    const float* iw2f = biasblk + 576;
    const float ib2s = biasblk[640];

    const int tid = threadIdx.x;
    const int wv = tid >> 6;
    const int lane = tid & 63;
    const int n15 = lane & 15;
    const int quad = lane >> 4;
    const int wb = blockIdx.x * 128 + wv * 32;

    int row_e[2], col_e[2];
    float dist[2], attr[2];
#pragma unroll
    for (int m = 0; m < 2; ++m) {
        int slot = wb + m * 16 + n15;
        int sL = (slot < E) ? slot : (E - 1);
        int eL = CSR ? elist[sL] : sL;
        row_e[m] = erow[eL];
        col_e[m] = ecol[eL];
        float d = 0.f;
#pragma unroll
        for (int dd = 0; dd < 3; ++dd) {
            float xd = ldf(x, row_e[m] * 3 + dd, flag) - ldf(x, col_e[m] * 3 + dd, flag);
            d += xd * xd;
        }
        dist[m] = d;
        attr[m] = ldf(eattr, eL, flag);
    }

    short8 cA[2][4];
#pragma unroll
    for (int m = 0; m < 2; ++m)
#pragma unroll
        for (int c = 0; c < 4; ++c)
            cA[m][c] = *(const short8*)(hb + col_e[m] * 128 + c * 32 + quad * 8);

    f32x4 acc1[2][8];
#pragma unroll
    for (int m = 0; m < 2; ++m)
#pragma unroll
        for (int nt = 0; nt < 8; ++nt) acc1[m][nt] = (f32x4){0.f, 0.f, 0.f, 0.f};

#pragma unroll
    for (int kc = 0; kc < 9; ++kc) {
        short8 a[2];
        if (kc < 4) {
            a[0] = *(const short8*)(hb + row_e[0] * 128 + kc * 32 + quad * 8);
            a[1] = *(const short8*)(hb + row_e[1] * 128 + kc * 32 + quad * 8);
        } else if (kc < 8) {
            a[0] = cA[0][kc - 4];
            a[1] = cA[1][kc - 4];
        } else {
#pragma unroll
            for (int m = 0; m < 2; ++m) {
#pragma unroll
                for (int t = 0; t < 8; ++t) a[m][t] = 0;
                if (quad == 0) { a[m][0] = f2bs_rn(dist[m]); a[m][1] = f2bs_rn(attr[m]); }
            }
        }
        const short* bp = W1f + (kc * 8) * 512 + lane * 8;
#pragma unroll
        for (int nt = 0; nt < 8; ++nt) {
            short8 b = *(const short8*)(bp + nt * 512);
            acc1[0][nt] = __builtin_amdgcn_mfma_f32_16x16x32_bf16(a[0], b, acc1[0][nt], 0, 0, 0);
            acc1[1][nt] = __builtin_amdgcn_mfma_f32_16x16x32_bf16(a[1], b, acc1[1][nt], 0, 0, 0);
        }
    }

#pragma unroll
    for (int m = 0; m < 2; ++m) {
        short* tl = tiles[wv * 2 + m];
#pragma unroll
        for (int nt = 0; nt < 8; ++nt) {
            float bv = b1f[nt * 16 + n15];
#pragma unroll
            for (int r = 0; r < 4; ++r)
                tl[(quad * 4 + r) * 136 + nt * 16 + n15] = f2bs_rn(siluf(acc1[m][nt][r] + bv));
        }
    }

    f32x4 acc2[2][8];
#pragma unroll
    for (int m = 0; m < 2; ++m)
#pragma unroll
        for (int nt = 0; nt < 8; ++nt) acc2[m][nt] = (f32x4){0.f, 0.f, 0.f, 0.f};
#pragma unroll
    for (int kc = 0; kc < 4; ++kc) {
        short8 a[2];
#pragma unroll
        for (int m = 0; m < 2; ++m)
            a[m] = *(const short8*)(tiles[wv * 2 + m] + n15 * 136 + kc * 32 + quad * 8);
        const short* bp = W2f + (kc * 8) * 512 + lane * 8;
#pragma unroll
        for (int nt = 0; nt < 8; ++nt) {
            short8 b = *(const short8*)(bp + nt * 512);
            acc2[0][nt] = __builtin_amdgcn_mfma_f32_16x16x32_bf16(a[0], b, acc2[0][nt], 0, 0, 0);
            acc2[1][nt] = __builtin_amdgcn_mfma_f32_16x16x32_bf16(a[1], b, acc2[1][nt], 0, 0, 0);
        }
    }

    float mv[2][8][4];
#pragma unroll
    for (int m = 0; m < 2; ++m) {
        short* tl = tiles[wv * 2 + m];
#pragma unroll
        for (int nt = 0; nt < 8; ++nt) {
            float bv = b2f[nt * 16 + n15];
#pragma unroll
            for (int r = 0; r < 4; ++r) {
                float v = siluf(acc2[m][nt][r] + bv);
                mv[m][nt][r] = v;
                tl[(quad * 4 + r) * 136 + nt * 16 + n15] = f2bs_rn(v);
            }
        }
    }

    f32x4 acc4[2][4];
#pragma unroll
    for (int m = 0; m < 2; ++m)
#pragma unroll
        for (int nt = 0; nt < 4; ++nt) acc4[m][nt] = (f32x4){0.f, 0.f, 0.f, 0.f};
#pragma unroll
    for (int kc = 0; kc < 4; ++kc) {
        short8 a[2];
#pragma unroll
        for (int m = 0; m < 2; ++m)
            a[m] = *(const short8*)(tiles[wv * 2 + m] + n15 * 136 + kc * 32 + quad * 8);
        const short* bp = iW1f + (kc * 4) * 512 + lane * 8;
#pragma unroll
        for (int nt = 0; nt < 4; ++nt) {
            short8 b = *(const short8*)(bp + nt * 512);
            acc4[0][nt] = __builtin_amdgcn_mfma_f32_16x16x32_bf16(a[0], b, acc4[0][nt], 0, 0, 0);
            acc4[1][nt] = __builtin_amdgcn_mfma_f32_16x16x32_bf16(a[1], b, acc4[1][nt], 0, 0, 0);
        }
    }
    float eij[2][4];
#pragma unroll
    for (int m = 0; m < 2; ++m) {
        float inp[4] = {0.f, 0.f, 0.f, 0.f};
#pragma unroll
        for (int nt = 0; nt < 4; ++nt) {
            float ib = ib1f[nt * 16 + n15];
            float iw = iw2f[nt * 16 + n15];
#pragma unroll
            for (int r = 0; r < 4; ++r) inp[r] += siluf(acc4[m][nt][r] + ib) * iw;
        }
#pragma unroll
        for (int mk = 1; mk < 16; mk <<= 1)
#pragma unroll
            for (int r = 0; r < 4; ++r) inp[r] += __shfl_xor(inp[r], mk);
#pragma unroll
        for (int r = 0; r < 4; ++r) eij[m][r] = sigmf(inp[r] + ib2s);
    }

    f32x4 acc3[2][8];
#pragma unroll
    for (int m = 0; m < 2; ++m)
#pragma unroll
        for (int nt = 0; nt < 8; ++nt) acc3[m][nt] = (f32x4){0.f, 0.f, 0.f, 0.f};
#pragma unroll
    for (int kc = 0; kc < 4; ++kc) {
        short8 a[2];
#pragma unroll
        for (int m = 0; m < 2; ++m)
            a[m] = *(const short8*)(tiles[wv * 2 + m] + n15 * 136 + kc * 32 + quad * 8);
        const short* bp = cW1f + (kc * 8) * 512 + lane * 8;
#pragma unroll
        for (int nt = 0; nt < 8; ++nt) {
            short8 b = *(const short8*)(bp + nt * 512);
            acc3[0][nt] = __builtin_amdgcn_mfma_f32_16x16x32_bf16(a[0], b, acc3[0][nt], 0, 0, 0);
            acc3[1][nt] = __builtin_amdgcn_mfma_f32_16x16x32_bf16(a[1], b, acc3[1][nt], 0, 0, 0);
        }
    }

#pragma unroll
    for (int m = 0; m < 2; ++m) {
        float php[4] = {0.f, 0.f, 0.f, 0.f};
#pragma unroll
        for (int nt = 0; nt < 8; ++nt) {
            float cb = cb1f[nt * 16 + n15];
            float cw = cw2f[nt * 16 + n15];
#pragma unroll
            for (int r = 0; r < 4; ++r) php[r] += siluf(acc3[m][nt][r] + cb) * cw;
        }
#pragma unroll
        for (int mk = 1; mk < 16; mk <<= 1)
#pragma unroll
            for (int r = 0; r < 4; ++r) php[r] += __shfl_xor(php[r], mk);

        const int ebase = wb + m * 16;
        int er[4], ec[4];
        bool mk4[4];
#pragma unroll
        for (int r = 0; r < 4; ++r) {
            er[r] = __shfl(row_e[m], quad * 4 + r);
            ec[r] = __shfl(col_e[m], quad * 4 + r);
            mk4[r] = (ebase + quad * 4 + r) < E;
        }

        if (n15 == 0) {
#pragma unroll
            for (int r = 0; r < 4; ++r) {
                if (!mk4[r]) continue;
                float s = eij[m][r] * php[r];
#pragma unroll
                for (int d = 0; d < 3; ++d) {
                    float xd = ldf(x, er[r] * 3 + d, flag) - ldf(x, ec[r] * 3 + d, flag);
                    atomicAdd(&agg_x[er[r] * 3 + d], nz(s * xd));
                }
            }
        }

        if (CSR) {
            int p = 0;
            while (p < 16 && (ebase + p) < E) {
                int rowp = __shfl(row_e[m], p);
                unsigned bal = (unsigned)__ballot(row_e[m] == rowp) & 0xFFFFu;
                unsigned bits = (~bal) >> p;
                int q = p + __builtin_ctz(bits);
                float s[8];
#pragma unroll
                for (int nt = 0; nt < 8; ++nt) s[nt] = 0.f;
#pragma unroll
                for (int r = 0; r < 4; ++r) {
                    int idx = quad * 4 + r;
                    bool in = (idx >= p) && (idx < q) && ((ebase + idx) < E);
                    float w = in ? eij[m][r] : 0.f;
#pragma unroll
                    for (int nt = 0; nt < 8; ++nt) s[nt] += w * mv[m][nt][r];
                }
#pragma unroll
                for (int nt = 0; nt < 8; ++nt) {
                    s[nt] += __shfl_xor(s[nt], 16);
                    s[nt] += __shfl_xor(s[nt], 32);
                }
                if (quad == 0) {
#pragma unroll
                    for (int nt = 0; nt < 8; ++nt)
                        atomicAdd(&m_i[(size_t)rowp * 128 + nt * 16 + n15], nz(s[nt]));
                }
                p = q;
            }
        } else {
#pragma unroll
            for (int nt = 0; nt < 8; ++nt)
#pragma unroll
                for (int r = 0; r < 4; ++r)
                    if (mk4[r]) atomicAdd(&m_i[er[r] * 128 + nt * 16 + n15],
                                          nz(eij[m][r] * mv[m][nt][r]));
        }
    }
}

// ---------------------------------------------------------------------------
extern "C" void kernel_launch(void* const* d_in, const int* in_sizes, int n_in,
                              void* d_out, int out_size, void* d_ws, size_t ws_size,
                              hipStream_t stream) {
    const void* h = d_in[0];
    const void* x = d_in[1];
    const void* eattr = d_in[2];
    const void* v_init = d_in[3];
    const int* eidx = (const int*)d_in[4];

    const int N = in_sizes[0] / 128;
    const int E = in_sizes[4] / 2;
    const int* erow = eidx;
    const int* ecol = eidx + E;

    char* ws = (char*)d_ws;
    int* flag = (int*)ws;                       // 256
    short* W1t = (short*)(ws + 256);            // 73728
    short* W2t = (short*)(ws + 73984);          // 32768
    short* cW1t = (short*)(ws + 106752);        // 32768
    short* iW1t = (short*)(ws + 139520);        // 16384
    float* biasblk = (float*)(ws + 155904);     // 1412 floats -> pad to 162048
    short* nW1b = (short*)(ws + 162048);        // 65536
    short* nW2b = (short*)(ws + 227584);        // 32768
    short* vW1b = (short*)(ws + 260352);        // 32768
    int* bsum = (int*)(ws + 293120);            // 512
    int* bpre = (int*)(ws + 293632);            // 512
    short* hb = (short*)(ws + 294144);          // N*256
    size_t o = 294144 + (size_t)N * 256;
    // zero region: cnt + cur + agg_x + m_i (contiguous)
    size_t oZero = o;
    int* cnt = (int*)(ws + o); o += (size_t)N * 4;
    int* cur = (int*)(ws + o); o += (size_t)N * 4;
    float* agg_x = (float*)(ws + o); o += (size_t)N * 12;
    float* m_i = (float*)(ws + o); o += (size_t)N * 512;
    size_t zeroBytes = o - oZero;
    // CSR extras
    int* offp = (int*)(ws + o); o += (size_t)(N + 16) * 4;
    int* elist = (int*)(ws + o); o += (size_t)E * 4;
    const size_t need_csr = o;
    // precomputed h@W1 partials (bf16 N x 128 each)
    short* hA = (short*)(ws + o); o += (size_t)N * 256;
    short* hB = (short*)(ws + o); o += (size_t)N * 256;
    const size_t need_full = o;

    const bool csr = (ws_size >= need_csr);
    const bool pre = (ws_size >= need_full);

    detect_kernel<<<1, 64, 0, stream>>>((const unsigned int*)h, flag);

    // memset early: zero region must be ready before convh_count's atomics
    hipMemsetAsync((void*)(ws + oZero), 0, zeroBytes, stream);

    const int prep_elems = 36864 + 16384 + 16384 + 8192 + 1412 + 32768 + 16384 + 16384;
    prep_kernel<<<(prep_elems + 255) / 256, 256, 0, stream>>>(
        d_in[5], d_in[7], d_in[9], d_in[12],
        d_in[6], d_in[8], d_in[10], d_in[11], d_in[13], d_in[14], d_in[15],
        d_in[17], d_in[19], d_in[21], d_in[22],
        d_in[16], d_in[18], d_in[20],
        W1t, W2t, cW1t, iW1t, biasblk, nW1b, nW2b, vW1b, flag);

    // fused convh + count (independent elementwise streams, one launch)
    {
        int total = (N * 128 > E) ? N * 128 : E;
        convh_count_kernel<<<(total + 255) / 256, 256, 0, stream>>>(
            h, hb, erow, cnt, flag, N * 128, E);
    }

    // CSR chain issued BEFORE hw1 so the small scan kernels overlap with the
    // larger hw1 MFMA kernel on-device (independent data).
    if (csr) {
        const int nb = (N + 1023) / 1024;
        scan1_kernel<<<nb, 1024, 0, stream>>>(cnt, offp, bsum, N);
        scan2_kernel<<<1, 1024, 0, stream>>>(bsum, bpre, nb);
        scan3_kernel<<<(N + 255) / 256, 256, 0, stream>>>(offp, bpre, N);
        fill_kernel<<<(E + 255) / 256, 256, 0, stream>>>(erow, offp, cur, elist, E);
    }

    if (pre) {
        hw1_kernel<<<(N + 127) / 128, 256, 0, stream>>>(hb, W1t, hA, hB, N);
    }

    if (pre && csr) {
        edge_kernel<true><<<(E + 63) / 64, 256, 0, stream>>>(
            hA, hB, x, eattr, erow, ecol, elist, W2t, cW1t, iW1t, biasblk,
            m_i, agg_x, E, flag);
    } else if (csr) {
        edge_kernel_old<true><<<(E + 127) / 128, 256, 0, stream>>>(
            hb, x, eattr, erow, ecol, elist, W1t, W2t, cW1t, iW1t, biasblk,
            m_i, agg_x, E, flag);
    } else {
        edge_kernel_old<false><<<(E + 127) / 128, 256, 0, stream>>>(
            hb, x, eattr, erow, ecol, nullptr, W1t, W2t, cW1t, iW1t, biasblk,
            m_i, agg_x, E, flag);
    }

    node_kernel<<<(N + 63) / 64, 256, 0, stream>>>(
        hb, x, v_init, cnt, m_i, agg_x,
        nW1b, nW2b, vW1b, biasblk, d_out, N, N * 128, N * 131,
        1.0f / (float)(N - 1), flag);
}

// Round 16
// 1044.518 us; speedup vs baseline: 1.0126x; 1.0126x over previous
//
#include <hip/hip_runtime.h>
#include <hip/hip_bf16.h>

typedef __attribute__((ext_vector_type(8))) short short8;
typedef __attribute__((ext_vector_type(4))) float f32x4;
typedef __hip_bfloat16 bf16;

__device__ __forceinline__ short f2bs_rn(float f) {   // fast RNE bf16 pack
    unsigned u = __builtin_bit_cast(unsigned, f);
    u += 0x7FFF + ((u >> 16) & 1);
    return (short)(u >> 16);
}
__device__ __forceinline__ float bs2f(short s) {
    unsigned u = ((unsigned)(unsigned short)s) << 16;
    return __builtin_bit_cast(float, u);
}
__device__ __forceinline__ float ldf(const void* p, int i, int flag) {
    return flag ? bs2f(((const short*)p)[i]) : ((const float*)p)[i];
}
__device__ __forceinline__ short ldbits(const void* p, int i, int flag) {
    return flag ? ((const short*)p)[i] : f2bs_rn(((const float*)p)[i]);
}
__device__ __forceinline__ void stf(void* p, int i, float v, int flag) {
    if (flag) ((bf16*)p)[i] = __float2bfloat16(v);
    else ((float*)p)[i] = v;
}
__device__ __forceinline__ float nz(float v) { return (v == v) ? v : 0.f; }
__device__ __forceinline__ float siluf(float v) {
    return v * __builtin_amdgcn_rcpf(1.f + __expf(-v));
}
__device__ __forceinline__ float sigmf(float v) {
    return __builtin_amdgcn_rcpf(1.f + __expf(-v));
}

// ---------------------------------------------------------------------------
__global__ void detect_kernel(const unsigned int* __restrict__ hw, int* __restrict__ flag) {
    unsigned int w = hw[threadIdx.x];
    unsigned int e = (w >> 7) & 0xFF;
    bool ok = (e >= 113 && e <= 135);
    unsigned long long m = __ballot(ok);
    if (threadIdx.x == 0) *flag = (__popcll(m) >= 32) ? 1 : 0;
}

// ---------------------------------------------------------------------------
// prep: ALL weights in MFMA B-fragment order:
//   frag chunk c = kc*NT + nt, element r = lane*8 + j
//   -> W[k = kc*32 + (lane>>4)*8 + j][n = nt*16 + (lane&15)]
// biasblk extended with W1 rows 256 (dist) / 257 (attr) at 1156 / 1284.
// ---------------------------------------------------------------------------
__global__ void prep_kernel(
    const void* eW1, const void* eW2, const void* cW1, const void* iW1,
    const void* eb1, const void* eb2, const void* cb1, const void* cw2,
    const void* ib1, const void* iw2, const void* ib2, const void* nb1,
    const void* nb2, const void* vb1, const void* vW2,
    const void* nW1, const void* nW2, const void* vW1,
    short* __restrict__ W1t, short* __restrict__ W2t,
    short* __restrict__ cW1t, short* __restrict__ iW1t,
    float* __restrict__ biasblk, short* __restrict__ nW1b,
    short* __restrict__ nW2b, short* __restrict__ vW1b,
    const int* __restrict__ flagp) {
    const int flag = *flagp;
    int i = blockIdx.x * 256 + threadIdx.x;
    if (i < 36864) {  // W1 fragments: 9 kc x 8 nt x 512
        int c = i >> 9, r = i & 511;
        int kc = c >> 3, nt = c & 7;
        int ln = r >> 3, j = r & 7;
        int k = kc * 32 + ((ln >> 4) << 3) + j;
        int n = nt * 16 + (ln & 15);
        W1t[i] = (k < 258) ? ldbits(eW1, k * 128 + n, flag) : (short)0;
        return;
    }
    i -= 36864;
    if (i < 16384) {  // W2 fragments: 4 kc x 8 nt
        int c = i >> 9, r = i & 511;
        int kc = c >> 3, nt = c & 7;
        int ln = r >> 3, j = r & 7;
        int k = kc * 32 + ((ln >> 4) << 3) + j;
        int n = nt * 16 + (ln & 15);
        W2t[i] = ldbits(eW2, k * 128 + n, flag);
        return;
    }
    i -= 16384;
    if (i < 16384) {  // coord W1 fragments: 4 kc x 8 nt
        int c = i >> 9, r = i & 511;
        int kc = c >> 3, nt = c & 7;
        int ln = r >> 3, j = r & 7;
        int k = kc * 32 + ((ln >> 4) << 3) + j;
        int n = nt * 16 + (ln & 15);
        cW1t[i] = ldbits(cW1, k * 128 + n, flag);
        return;
    }
    i -= 16384;
    if (i < 8192) {  // inf W1 fragments: 4 kc x 4 nt
        int c = i >> 9, r = i & 511;
        int kc = c >> 2, nt = c & 3;
        int ln = r >> 3, j = r & 7;
        int k = kc * 32 + ((ln >> 4) << 3) + j;
        int n = nt * 16 + (ln & 15);
        iW1t[i] = ldbits(iW1, k * 64 + n, flag);
        return;
    }
    i -= 8192;
    if (i < 1412) {
        float v;
        if (i < 128) v = ldf(eb1, i, flag);
        else if (i < 256) v = ldf(eb2, i - 128, flag);
        else if (i < 384) v = ldf(cb1, i - 256, flag);
        else if (i < 512) v = ldf(cw2, i - 384, flag);
        else if (i < 576) v = ldf(ib1, i - 512, flag);
        else if (i < 640) v = ldf(iw2, i - 576, flag);
        else if (i < 644) v = (i == 640) ? ldf(ib2, 0, flag) : 0.f;
        else if (i < 772) v = ldf(nb1, i - 644, flag);
        else if (i < 900) v = ldf(nb2, i - 772, flag);
        else if (i < 1028) v = ldf(vb1, i - 900, flag);
        else if (i < 1156) v = ldf(vW2, i - 1028, flag);
        else if (i < 1284) v = ldf(eW1, 256 * 128 + (i - 1156), flag);  // dist row
        else v = ldf(eW1, 257 * 128 + (i - 1284), flag);                // attr row
        biasblk[i] = v;
        return;
    }
    i -= 1412;
    if (i < 32768) {  // node W1 fragments: 8 kc x 8 nt
        int c = i >> 9, r = i & 511;
        int kc = c >> 3, nt = c & 7;
        int ln = r >> 3, j = r & 7;
        int k = kc * 32 + ((ln >> 4) << 3) + j;
        int n = nt * 16 + (ln & 15);
        nW1b[i] = ldbits(nW1, k * 128 + n, flag);
        return;
    }
    i -= 32768;
    if (i < 16384) {  // node W2 fragments: 4 kc x 8 nt
        int c = i >> 9, r = i & 511;
        int kc = c >> 3, nt = c & 7;
        int ln = r >> 3, j = r & 7;
        int k = kc * 32 + ((ln >> 4) << 3) + j;
        int n = nt * 16 + (ln & 15);
        nW2b[i] = ldbits(nW2, k * 128 + n, flag);
        return;
    }
    i -= 16384;
    if (i < 16384) {  // vel W1 fragments: 4 kc x 8 nt
        int c = i >> 9, r = i & 511;
        int kc = c >> 3, nt = c & 7;
        int ln = r >> 3, j = r & 7;
        int k = kc * 32 + ((ln >> 4) << 3) + j;
        int n = nt * 16 + (ln & 15);
        vW1b[i] = ldbits(vW1, k * 128 + n, flag);
    }
}

// ---------------------------------------------------------------------------
__global__ void convh_kernel(const void* __restrict__ h, short* __restrict__ hb,
                             const int* __restrict__ flagp, int n) {
    const int flag = *flagp;
    int i = blockIdx.x * 256 + threadIdx.x;
    if (i < n) hb[i] = ldbits(h, i, flag);
}

// ---------------------------------------------------------------------------
// hw1: precompute hA = h @ W1[0:128], hB = h @ W1[128:256] (bf16, N x 128).
// ---------------------------------------------------------------------------
__global__ __launch_bounds__(256) void hw1_kernel(
    const short* __restrict__ hb, const short* __restrict__ W1t,
    short* __restrict__ hA, short* __restrict__ hB, int N) {
    const int tid = threadIdx.x;
    const int wv = tid >> 6;
    const int lane = tid & 63;
    const int n15 = lane & 15;
    const int quad = lane >> 4;
    const int base = blockIdx.x * 128 + wv * 32;

    f32x4 accA[2][8], accB[2][8];
#pragma unroll
    for (int m = 0; m < 2; ++m)
#pragma unroll
        for (int nt = 0; nt < 8; ++nt) {
            accA[m][nt] = (f32x4){0.f, 0.f, 0.f, 0.f};
            accB[m][nt] = (f32x4){0.f, 0.f, 0.f, 0.f};
        }

#pragma unroll
    for (int kc = 0; kc < 4; ++kc) {
        short8 a[2];
#pragma unroll
        for (int m = 0; m < 2; ++m) {
            int node = base + m * 16 + n15;
            if (node >= N) node = N - 1;
            a[m] = *(const short8*)(hb + node * 128 + kc * 32 + quad * 8);
        }
        const short* bpA = W1t + (kc * 8) * 512 + lane * 8;
        const short* bpB = W1t + ((kc + 4) * 8) * 512 + lane * 8;
#pragma unroll
        for (int nt = 0; nt < 8; ++nt) {
            short8 ba = *(const short8*)(bpA + nt * 512);
            short8 bb = *(const short8*)(bpB + nt * 512);
            accA[0][nt] = __builtin_amdgcn_mfma_f32_16x16x32_bf16(a[0], ba, accA[0][nt], 0, 0, 0);
            accA[1][nt] = __builtin_amdgcn_mfma_f32_16x16x32_bf16(a[1], ba, accA[1][nt], 0, 0, 0);
            accB[0][nt] = __builtin_amdgcn_mfma_f32_16x16x32_bf16(a[0], bb, accB[0][nt], 0, 0, 0);
            accB[1][nt] = __builtin_amdgcn_mfma_f32_16x16x32_bf16(a[1], bb, accB[1][nt], 0, 0, 0);
        }
    }

#pragma unroll
    for (int m = 0; m < 2; ++m)
#pragma unroll
        for (int nt = 0; nt < 8; ++nt)
#pragma unroll
            for (int r = 0; r < 4; ++r) {
                int node = base + m * 16 + quad * 4 + r;
                if (node < N) {
                    hA[node * 128 + nt * 16 + n15] = f2bs_rn(accA[m][nt][r]);
                    hB[node * 128 + nt * 16 + n15] = f2bs_rn(accB[m][nt][r]);
                }
            }
}

// ---------------------------------------------------------------------------
// CSR build
// ---------------------------------------------------------------------------
__global__ void count_kernel(const int* __restrict__ erow, int* __restrict__ cnt, int E) {
    int i = blockIdx.x * 256 + threadIdx.x;
    if (i < E) atomicAdd(&cnt[erow[i]], 1);
}

__global__ __launch_bounds__(1024) void scan1_kernel(const int* __restrict__ cnt,
                                                     int* __restrict__ off,
                                                     int* __restrict__ bsum, int N) {
    __shared__ int sm[1024];
    int t = threadIdx.x, i = blockIdx.x * 1024 + t;
    int c = (i < N) ? cnt[i] : 0;
    sm[t] = c;
    __syncthreads();
    for (int d = 1; d < 1024; d <<= 1) {
        int v = (t >= d) ? sm[t - d] : 0;
        __syncthreads();
        sm[t] += v;
        __syncthreads();
    }
    if (i < N) off[i] = sm[t] - c;
    if (t == 1023) bsum[blockIdx.x] = sm[1023];
}
__global__ void scan2_kernel(const int* __restrict__ bsum, int* __restrict__ bpre, int nb) {
    if (threadIdx.x == 0) {
        int run = 0;
        for (int b = 0; b < nb; ++b) { bpre[b] = run; run += bsum[b]; }
    }
}
__global__ void scan3_kernel(int* __restrict__ off, const int* __restrict__ bpre, int N) {
    int i = blockIdx.x * 256 + threadIdx.x;
    if (i < N) off[i] += bpre[i >> 10];
}
__global__ void fill_kernel(const int* __restrict__ erow, const int* __restrict__ off,
                            int* __restrict__ cur, int* __restrict__ elist, int E) {
    int i = blockIdx.x * 256 + threadIdx.x;
    if (i < E) {
        int r = erow[i];
        int p = off[r] + atomicAdd(&cur[r], 1);
        elist[p] = i;
    }
}

// ---------------------------------------------------------------------------
// edge kernel (PRE path): 4 waves x 16 edges, one m-tile per wave.
// (256,5): measured optimum of the occupancy sweep (4blk=573us, 5blk=535us,
// 6blk=632us). hidden1 in registers; XCD swizzle; merged segment reduction.
// ---------------------------------------------------------------------------
template <bool CSR>
__global__ __launch_bounds__(256, 5) void edge_kernel(
    const short* __restrict__ hA, const short* __restrict__ hB,
    const void* __restrict__ x, const void* __restrict__ eattr,
    const int* __restrict__ erow, const int* __restrict__ ecol,
    const int* __restrict__ elist,
    const short* __restrict__ W2f, const short* __restrict__ cW1f,
    const short* __restrict__ iW1f,
    const float* __restrict__ biasblk,
    float* __restrict__ m_i, float* __restrict__ agg_x, int E,
    const int* __restrict__ flagp) {
    const int flag = *flagp;
    __shared__ __align__(16) short tiles[4][16 * 136];  // 17408 B
    const float* b1f = biasblk;
    const float* b2f = biasblk + 128;
    const float* cb1f = biasblk + 256;
    const float* cw2f = biasblk + 384;
    const float* ib1f = biasblk + 512;
    const float* iw2f = biasblk + 576;
    const float ib2s = biasblk[640];
    const float* w1df = biasblk + 1156;
    const float* w1af = biasblk + 1284;

    // bijective chunked XCD swizzle (m204): consecutive CSR tiles -> same XCD.
    int bid;
    {
        const int nwg = gridDim.x;
        const int qq = nwg >> 3, r8 = nwg & 7;
        const int xcd = blockIdx.x & 7, idx = blockIdx.x >> 3;
        const int base = (xcd < r8) ? xcd * (qq + 1) : r8 * (qq + 1) + (xcd - r8) * qq;
        bid = base + idx;
    }

    const int tid = threadIdx.x;
    const int wv = tid >> 6;
    const int lane = tid & 63;
    const int n15 = lane & 15;
    const int quad = lane >> 4;
    const int wb = bid * 64 + wv * 16;

    int row_e, col_e;
    float dist, attr;
    {
        int slot = wb + n15;
        int sL = (slot < E) ? slot : (E - 1);
        int eL = CSR ? elist[sL] : sL;
        row_e = erow[eL];
        col_e = ecol[eL];
        float d = 0.f;
#pragma unroll
        for (int dd = 0; dd < 3; ++dd) {
            float xd = ldf(x, row_e * 3 + dd, flag) - ldf(x, col_e * 3 + dd, flag);
            d += xd * xd;
        }
        dist = d;
        attr = ldf(eattr, eL, flag);
    }

    // ---- col partial gather (random, L3 latency): 16 VGPR
    short8 cB[4];
#pragma unroll
    for (int c = 0; c < 4; ++c)
        cB[c] = *(const short8*)(hB + col_e * 128 + c * 32 + quad * 8);

    // ---- m1 = hA[row] + hB[col] + dist*W1d + attr*W1at + b1 -> silu
    // kept in REGISTERS: combine layout (row n15, col c*32+quad*8) is exactly
    // GEMM2's A-fragment layout for this lane. No LDS round-trip.
    short* tl = tiles[wv];
    short8 h1[4];
#pragma unroll
    for (int c = 0; c < 4; ++c) {
        short8 ra = *(const short8*)(hA + row_e * 128 + c * 32 + quad * 8);
        short8 ov;
#pragma unroll
        for (int j = 0; j < 8; ++j) {
            int f = c * 32 + quad * 8 + j;
            float v = bs2f(ra[j]) + bs2f(cB[c][j])
                    + dist * w1df[f] + attr * w1af[f] + b1f[f];
            ov[j] = f2bs_rn(siluf(v));
        }
        h1[c] = ov;
    }

    // ---- GEMM2: hidden1 @ W2 (A straight from registers)
    f32x4 acc2[8];
#pragma unroll
    for (int nt = 0; nt < 8; ++nt) acc2[nt] = (f32x4){0.f, 0.f, 0.f, 0.f};
#pragma unroll
    for (int kc = 0; kc < 4; ++kc) {
        short8 a = h1[kc];
        const short* bp = W2f + (kc * 8) * 512 + lane * 8;
#pragma unroll
        for (int nt = 0; nt < 8; ++nt) {
            short8 b = *(const short8*)(bp + nt * 512);
            acc2[nt] = __builtin_amdgcn_mfma_f32_16x16x32_bf16(a, b, acc2[nt], 0, 0, 0);
        }
    }

    // mv (bf16) -> LDS tile (C-layout transpose); needed by GEMM3/4 + m_i.
#pragma unroll
    for (int nt = 0; nt < 8; ++nt) {
        float bv = b2f[nt * 16 + n15];
#pragma unroll
        for (int r = 0; r < 4; ++r)
            tl[(quad * 4 + r) * 136 + nt * 16 + n15] = f2bs_rn(siluf(acc2[nt][r] + bv));
    }

    // ---- GEMM4 (inf, 64 cols) -> eij
    f32x4 acc4[4];
#pragma unroll
    for (int nt = 0; nt < 4; ++nt) acc4[nt] = (f32x4){0.f, 0.f, 0.f, 0.f};
#pragma unroll
    for (int kc = 0; kc < 4; ++kc) {
        short8 a = *(const short8*)(tl + n15 * 136 + kc * 32 + quad * 8);
        const short* bp = iW1f + (kc * 4) * 512 + lane * 8;
#pragma unroll
        for (int nt = 0; nt < 4; ++nt) {
            short8 b = *(const short8*)(bp + nt * 512);
            acc4[nt] = __builtin_amdgcn_mfma_f32_16x16x32_bf16(a, b, acc4[nt], 0, 0, 0);
        }
    }
    float eij[4];
    {
        float inp[4] = {0.f, 0.f, 0.f, 0.f};
#pragma unroll
        for (int nt = 0; nt < 4; ++nt) {
            float ib = ib1f[nt * 16 + n15];
            float iw = iw2f[nt * 16 + n15];
#pragma unroll
            for (int r = 0; r < 4; ++r) inp[r] += siluf(acc4[nt][r] + ib) * iw;
        }
#pragma unroll
        for (int mk = 1; mk < 16; mk <<= 1)
#pragma unroll
            for (int r = 0; r < 4; ++r) inp[r] += __shfl_xor(inp[r], mk);
#pragma unroll
        for (int r = 0; r < 4; ++r) eij[r] = sigmf(inp[r] + ib2s);
    }

    // ---- GEMM3 (coord) -> phi
    f32x4 acc3[8];
#pragma unroll
    for (int nt = 0; nt < 8; ++nt) acc3[nt] = (f32x4){0.f, 0.f, 0.f, 0.f};
#pragma unroll
    for (int kc = 0; kc < 4; ++kc) {
        short8 a = *(const short8*)(tl + n15 * 136 + kc * 32 + quad * 8);
        const short* bp = cW1f + (kc * 8) * 512 + lane * 8;
#pragma unroll
        for (int nt = 0; nt < 8; ++nt) {
            short8 b = *(const short8*)(bp + nt * 512);
            acc3[nt] = __builtin_amdgcn_mfma_f32_16x16x32_bf16(a, b, acc3[nt], 0, 0, 0);
        }
    }

    // ---- epilogue + aggregation
    {
        float php[4] = {0.f, 0.f, 0.f, 0.f};
#pragma unroll
        for (int nt = 0; nt < 8; ++nt) {
            float cb = cb1f[nt * 16 + n15];
            float cw = cw2f[nt * 16 + n15];
#pragma unroll
            for (int r = 0; r < 4; ++r) php[r] += siluf(acc3[nt][r] + cb) * cw;
        }
#pragma unroll
        for (int mk = 1; mk < 16; mk <<= 1)
#pragma unroll
            for (int r = 0; r < 4; ++r) php[r] += __shfl_xor(php[r], mk);
        // php[r]/eij[r] now uniform across n15 within each quad

        // distribute per-edge s = eij*php to the lane owning edge n15:
        // source quad = n15>>2, slot r = n15&3
        float sv[4];
#pragma unroll
        for (int r = 0; r < 4; ++r) sv[r] = eij[r] * php[r];
        const int srcl = (n15 >> 2) * 16;
        float t0 = __shfl(sv[0], srcl);
        float t1 = __shfl(sv[1], srcl);
        float t2 = __shfl(sv[2], srcl);
        float t3 = __shfl(sv[3], srcl);
        const int rr = n15 & 3;
        float s_e = (rr == 0) ? t0 : (rr == 1) ? t1 : (rr == 2) ? t2 : t3;

        // per-lane dim contribution: quad = dim (quad 3 idle)
        float val = 0.f;
        if (quad < 3) {
            float xd = ldf(x, row_e * 3 + quad, flag) - ldf(x, col_e * 3 + quad, flag);
            val = ((wb + n15) < E) ? nz(s_e * xd) : 0.f;
        }

        const int ebase = wb;
        if (CSR) {
            // merged segment loop: m_i (LDS mv) + agg_x, one atomic set per row
            int p = 0;
            while (p < 16 && (ebase + p) < E) {
                int rowp = __shfl(row_e, p);
                unsigned bal = (unsigned)__ballot(row_e == rowp) & 0xFFFFu;
                unsigned bits = (~bal) >> p;  // bit16 of ~bal is set -> bounded
                int q = p + __builtin_ctz(bits);

                // agg_x: sum val over n15 in [p,q) within each quad (dim)
                float av = (n15 >= p && n15 < q) ? val : 0.f;
#pragma unroll
                for (int mk = 1; mk < 16; mk <<= 1) av += __shfl_xor(av, mk);
                if (n15 == 0 && quad < 3) atomicAdd(&agg_x[rowp * 3 + quad], av);

                // m_i: weighted sum of LDS mv rows
                float s[8];
#pragma unroll
                for (int nt = 0; nt < 8; ++nt) s[nt] = 0.f;
#pragma unroll
                for (int r = 0; r < 4; ++r) {
                    int idx = quad * 4 + r;
                    bool in = (idx >= p) && (idx < q) && ((ebase + idx) < E);
                    float w = in ? eij[r] : 0.f;
#pragma unroll
                    for (int nt = 0; nt < 8; ++nt)
                        s[nt] += w * bs2f(tl[idx * 136 + nt * 16 + n15]);
                }
#pragma unroll
                for (int nt = 0; nt < 8; ++nt) {
                    s[nt] += __shfl_xor(s[nt], 16);
                    s[nt] += __shfl_xor(s[nt], 32);
                }
                if (quad == 0) {
#pragma unroll
                    for (int nt = 0; nt < 8; ++nt)
                        atomicAdd(&m_i[(size_t)rowp * 128 + nt * 16 + n15], nz(s[nt]));
                }
                p = q;
            }
        } else {
            // per-edge fallback (rows unsorted): lane-parallel agg_x
            if (quad < 3 && (wb + n15) < E)
                atomicAdd(&agg_x[row_e * 3 + quad], val);
#pragma unroll
            for (int nt = 0; nt < 8; ++nt)
#pragma unroll
                for (int r = 0; r < 4; ++r) {
                    int idx = quad * 4 + r;
                    if ((ebase + idx) < E) {
                        int er = __shfl(row_e, idx);
                        atomicAdd(&m_i[er * 128 + nt * 16 + n15],
                                  nz(eij[r] * bs2f(tl[idx * 136 + nt * 16 + n15])));
                    }
                }
        }
    }
}

// ---------------------------------------------------------------------------
// node kernel (MFMA): round-9 proven version, unchanged.
// ---------------------------------------------------------------------------
__global__ __launch_bounds__(256, 4) void node_kernel(
    const short* __restrict__ hb, const void* __restrict__ x,
    const void* __restrict__ v_init,
    const int* __restrict__ cnt,
    const float* __restrict__ m_i, const float* __restrict__ agg_x,
    const short* __restrict__ nW1f, const short* __restrict__ nW2f,
    const short* __restrict__ vW1f, const float* __restrict__ biasblk,
    void* __restrict__ out, int N, int xbase, int vbase, float inv_nm1,
    const int* __restrict__ flagp) {
    const int flag = *flagp;
    __shared__ __align__(16) short tiles[4][16 * 136];  // 17408 B
    const float* nb1f = biasblk + 644;
    const float* nb2f = biasblk + 772;
    const float* vb1f = biasblk + 900;
    const float* vW2f = biasblk + 1028;

    const int tid = threadIdx.x;
    const int wv = tid >> 6;
    const int lane = tid & 63;
    const int n15 = lane & 15;
    const int quad = lane >> 4;
    const int base = blockIdx.x * 64 + wv * 16;

    short* tl = tiles[wv];

    // ---- stage m_i (bf16 + nz) into tile: row n15, col c*32+quad*8..+8
    {
        int node = base + n15;
        if (node >= N) node = N - 1;
#pragma unroll
        for (int c = 0; c < 4; ++c) {
            const float* mp = m_i + (size_t)node * 128 + c * 32 + quad * 8;
            short8 ov;
#pragma unroll
            for (int j = 0; j < 8; ++j) ov[j] = f2bs_rn(nz(mp[j]));
            *(short8*)(tl + n15 * 136 + c * 32 + quad * 8) = ov;
        }
    }
    int anode = base + n15;
    if (anode >= N) anode = N - 1;

    // ---- vel GEMM: h @ vW1 -> silu -> * vW2 -> row-reduce -> vscale
    f32x4 acc[8];
#pragma unroll
    for (int nt = 0; nt < 8; ++nt) acc[nt] = (f32x4){0.f, 0.f, 0.f, 0.f};
#pragma unroll
    for (int kc = 0; kc < 4; ++kc) {
        short8 a = *(const short8*)(hb + (size_t)anode * 128 + kc * 32 + quad * 8);
        const short* bp = vW1f + (kc * 8) * 512 + lane * 8;
#pragma unroll
        for (int nt = 0; nt < 8; ++nt) {
            short8 b = *(const short8*)(bp + nt * 512);
            acc[nt] = __builtin_amdgcn_mfma_f32_16x16x32_bf16(a, b, acc[nt], 0, 0, 0);
        }
    }
    float vsc[4] = {0.f, 0.f, 0.f, 0.f};
#pragma unroll
    for (int nt = 0; nt < 8; ++nt) {
        int j = nt * 16 + n15;
        float vb = vb1f[j];
        float vw = vW2f[j];
#pragma unroll
        for (int r = 0; r < 4; ++r) vsc[r] += siluf(acc[nt][r] + vb) * vw;
    }
#pragma unroll
    for (int mk = 1; mk < 16; mk <<= 1)
#pragma unroll
        for (int r = 0; r < 4; ++r) vsc[r] += __shfl_xor(vsc[r], mk);

    // ---- node GEMM1: [h | m_i] @ nW1 -> silu -> tile
#pragma unroll
    for (int nt = 0; nt < 8; ++nt) acc[nt] = (f32x4){0.f, 0.f, 0.f, 0.f};
#pragma unroll
    for (int kc = 0; kc < 8; ++kc) {
        short8 a;
        if (kc < 4) a = *(const short8*)(hb + (size_t)anode * 128 + kc * 32 + quad * 8);
        else        a = *(const short8*)(tl + n15 * 136 + (kc - 4) * 32 + quad * 8);
        const short* bp = nW1f + (kc * 8) * 512 + lane * 8;
#pragma unroll
        for (int nt = 0; nt < 8; ++nt) {
            short8 b = *(const short8*)(bp + nt * 512);
            acc[nt] = __builtin_amdgcn_mfma_f32_16x16x32_bf16(a, b, acc[nt], 0, 0, 0);
        }
    }
#pragma unroll
    for (int nt = 0; nt < 8; ++nt) {
        float bv = nb1f[nt * 16 + n15];
#pragma unroll
        for (int r = 0; r < 4; ++r)
            tl[(quad * 4 + r) * 136 + nt * 16 + n15] = f2bs_rn(siluf(acc[nt][r] + bv));
    }

    // ---- node GEMM2: hidden @ nW2 -> out
#pragma unroll
    for (int nt = 0; nt < 8; ++nt) acc[nt] = (f32x4){0.f, 0.f, 0.f, 0.f};
#pragma unroll
    for (int kc = 0; kc < 4; ++kc) {
        short8 a = *(const short8*)(tl + n15 * 136 + kc * 32 + quad * 8);
        const short* bp = nW2f + (kc * 8) * 512 + lane * 8;
#pragma unroll
        for (int nt = 0; nt < 8; ++nt) {
            short8 b = *(const short8*)(bp + nt * 512);
            acc[nt] = __builtin_amdgcn_mfma_f32_16x16x32_bf16(a, b, acc[nt], 0, 0, 0);
        }
    }
#pragma unroll
    for (int nt = 0; nt < 8; ++nt) {
        float bv = nb2f[nt * 16 + n15];
#pragma unroll
        for (int r = 0; r < 4; ++r) {
            int node = base + quad * 4 + r;
            if (node < N) stf(out, node * 128 + nt * 16 + n15, nz(acc[nt][r] + bv), flag);
        }
    }

    // ---- x / v outputs (3 dims per node; lanes n15<3 of each quad)
    if (n15 < 3) {
#pragma unroll
        for (int r = 0; r < 4; ++r) {
            int node = base + quad * 4 + r;
            if (node >= N) continue;
            int d = n15;
            float vj = nz(ldf(v_init, node * 3 + d, flag) * vsc[r]);
            stf(out, vbase + node * 3 + d, vj, flag);
            float xv = ldf(x, node * 3 + d, flag);
            float xo = (cnt[node] > 0) ? xv + vj + nz(agg_x[node * 3 + d]) * inv_nm1 : xv;
            stf(out, xbase + node * 3 + d, nz(xo), flag);
        }
    }
}

// ---------------------------------------------------------------------------
// legacy edge kernel (round-2 exact): used only when workspace too small.
// ---------------------------------------------------------------------------
template <bool CSR>
__global__ __launch_bounds__(256, 2) void edge_kernel_old(
    const short* __restrict__ hb, const void* __restrict__ x,
    const void* __restrict__ eattr,
    const int* __restrict__ erow, const int* __restrict__ ecol,
    const int* __restrict__ elist,
    const short* __restrict__ W1f, const short* __restrict__ W2f,
    const short* __restrict__ cW1f, const short* __restrict__ iW1f,
    const float* __restrict__ biasblk,
    float* __restrict__ m_i, float* __restrict__ agg_x, int E,
    const int* __restrict__ flagp) {
    const int flag = *flagp;
    __shared__ __align__(16) short tiles[8][16 * 136];
    const float* b1f = biasblk;
    const float* b2f = biasblk + 128;
    const float* cb1f = biasblk + 256;
    const float* cw2f = biasblk + 384;
    const float* ib1f = biasblk + 512;
    const float* iw2f = biasblk + 576;
    const float ib2s = biasblk[640];

    const int tid = threadIdx.x;
    const int wv = tid >> 6;
    const int lane = tid & 63;
    const int n15 = lane & 15;
    const int quad = lane >> 4;
    const int wb = blockIdx.x * 128 + wv * 32;

    int row_e[2], col_e[2];
    float dist[2], attr[2];
#pragma unroll
    for (int m = 0; m < 2; ++m) {
        int slot = wb + m * 16 + n15;
        int sL = (slot < E) ? slot : (E - 1);
        int eL = CSR ? elist[sL] : sL;
        row_e[m] = erow[eL];
        col_e[m] = ecol[eL];
        float d = 0.f;
#pragma unroll
        for (int dd = 0; dd < 3; ++dd) {
            float xd = ldf(x, row_e[m] * 3 + dd, flag) - ldf(x, col_e[m] * 3 + dd, flag);
            d += xd * xd;
        }
        dist[m] = d;
        attr[m] = ldf(eattr, eL, flag);
    }

    short8 cA[2][4];
#pragma unroll
    for (int m = 0; m < 2; ++m)
#pragma unroll
        for (int c = 0; c < 4; ++c)
            cA[m][c] = *(const short8*)(hb + col_e[m] * 128 + c * 32 + quad * 8);

    f32x4 acc1[2][8];
#pragma unroll
    for (int m = 0; m < 2; ++m)
#pragma unroll
        for (int nt = 0; nt < 8; ++nt) acc1[m][nt] = (f32x4){0.f, 0.f, 0.f, 0.f};

#pragma unroll
    for (int kc = 0; kc < 9; ++kc) {
        short8 a[2];
        if (kc < 4) {
            a[0] = *(const short8*)(hb + row_e[0] * 128 + kc * 32 + quad * 8);
            a[1] = *(const short8*)(hb + row_e[1] * 128 + kc * 32 + quad * 8);
        } else if (kc < 8) {
            a[0] = cA[0][kc - 4];
            a[1] = cA[1][kc - 4];
        } else {
#pragma unroll
            for (int m = 0; m < 2; ++m) {
#pragma unroll
                for (int t = 0; t < 8; ++t) a[m][t] = 0;
                if (quad == 0) { a[m][0] = f2bs_rn(dist[m]); a[m][1] = f2bs_rn(attr[m]); }
            }
        }
        const short* bp = W1f + (kc * 8) * 512 + lane * 8;
#pragma unroll
        for (int nt = 0; nt < 8; ++nt) {
            short8 b = *(const short8*)(bp + nt * 512);
            acc1[0][nt] = __builtin_amdgcn_mfma_f32_16x16x32_bf16(a[0], b, acc1[0][nt], 0, 0, 0);
            acc1[1][nt] = __builtin_amdgcn_mfma_f32_16x16x32_bf16(a[1], b, acc1[1][nt], 0, 0, 0);
        }
    }

#pragma unroll
    for (int m = 0; m < 2; ++m) {
        short* tl = tiles[wv * 2 + m];
#pragma unroll
        for (int nt = 0; nt < 8; ++nt) {
            float bv = b1f[nt * 16 + n15];
#pragma unroll
            for (int r = 0; r < 4; ++r)
                tl[(quad * 4 + r) * 136 + nt * 16 + n15] = f2bs_rn(siluf(acc1[m][nt][r] + bv));
        }
    }

    f32x4 acc2[2][8];
#pragma unroll
    for (int m = 0; m < 2; ++m)
#pragma unroll
        for (int nt = 0; nt < 8; ++nt) acc2[m][nt] = (f32x4){0.f, 0.f, 0.f, 0.f};
#pragma unroll
    for (int kc = 0; kc < 4; ++kc) {
        short8 a[2];
#pragma unroll
        for (int m = 0; m < 2; ++m)
            a[m] = *(const short8*)(tiles[wv * 2 + m] + n15 * 136 + kc * 32 + quad * 8);
        const short* bp = W2f + (kc * 8) * 512 + lane * 8;
#pragma unroll
        for (int nt = 0; nt < 8; ++nt) {
            short8 b = *(const short8*)(bp + nt * 512);
            acc2[0][nt] = __builtin_amdgcn_mfma_f32_16x16x32_bf16(a[0], b, acc2[0][nt], 0, 0, 0);
            acc2[1][nt] = __builtin_amdgcn_mfma_f32_16x16x32_bf16(a[1], b, acc2[1][nt], 0, 0, 0);
        }
    }

    float mv[2][8][4];
#pragma unroll
    for (int m = 0; m < 2; ++m) {
        short* tl = tiles[wv * 2 + m];
#pragma unroll
        for (int nt = 0; nt < 8; ++nt) {
            float bv = b2f[nt * 16 + n15];
#pragma unroll
            for (int r = 0; r < 4; ++r) {
                float v = siluf(acc2[m][nt][r] + bv);
                mv[m][nt][r] = v;
                tl[(quad * 4 + r) * 136 + nt * 16 + n15] = f2bs_rn(v);
            }
        }
    }

    f32x4 acc4[2][4];
#pragma unroll
    for (int m = 0; m < 2; ++m)
#pragma unroll
        for (int nt = 0; nt < 4; ++nt) acc4[m][nt] = (f32x4){0.f, 0.f, 0.f, 0.f};
#pragma unroll
    for (int kc = 0; kc < 4; ++kc) {
        short8 a[2];
#pragma unroll
        for (int m = 0; m < 2; ++m)
            a[m] = *(const short8*)(tiles[wv * 2 + m] + n15 * 136 + kc * 32 + quad * 8);
        const short* bp = iW1f + (kc * 4) * 512 + lane * 8;
#pragma unroll
        for (int nt = 0; nt < 4; ++nt) {
            short8 b = *(const short8*)(bp + nt * 512);
            acc4[0][nt] = __builtin_amdgcn_mfma_f32_16x16x32_bf16(a[0], b, acc4[0][nt], 0, 0, 0);
            acc4[1][nt] = __builtin_amdgcn_mfma_f32_16x16x32_bf16(a[1], b, acc4[1][nt], 0, 0, 0);
        }
    }
    float eij[2][4];
#pragma unroll
    for (int m = 0; m < 2; ++m) {
        float inp[4] = {0.f, 0.f, 0.f, 0.f};
#pragma unroll
        for (int nt = 0; nt < 4; ++nt) {
            float ib = ib1f[nt * 16 + n15];
            float iw = iw2f[nt * 16 + n15];
#pragma unroll
            for (int r = 0; r < 4; ++r) inp[r] += siluf(acc4[m][nt][r] + ib) * iw;
        }
#pragma unroll
        for (int mk = 1; mk < 16; mk <<= 1)
#pragma unroll
            for (int r = 0; r < 4; ++r) inp[r] += __shfl_xor(inp[r], mk);
#pragma unroll
        for (int r = 0; r < 4; ++r) eij[m][r] = sigmf(inp[r] + ib2s);
    }

    f32x4 acc3[2][8];
#pragma unroll
    for (int m = 0; m < 2; ++m)
#pragma unroll
        for (int nt = 0; nt < 8; ++nt) acc3[m][nt] = (f32x4){0.f, 0.f, 0.f, 0.f};
#pragma unroll
    for (int kc = 0; kc < 4; ++kc) {
        short8 a[2];
#pragma unroll
        for (int m = 0; m < 2; ++m)
            a[m] = *(const short8*)(tiles[wv * 2 + m] + n15 * 136 + kc * 32 + quad * 8);
        const short* bp = cW1f + (kc * 8) * 512 + lane * 8;
#pragma unroll
        for (int nt = 0; nt < 8; ++nt) {
            short8 b = *(const short8*)(bp + nt * 512);
            acc3[0][nt] = __builtin_amdgcn_mfma_f32_16x16x32_bf16(a[0], b, acc3[0][nt], 0, 0, 0);
            acc3[1][nt] = __builtin_amdgcn_mfma_f32_16x16x32_bf16(a[1], b, acc3[1][nt], 0, 0, 0);
        }
    }

#pragma unroll
    for (int m = 0; m < 2; ++m) {
        float php[4] = {0.f, 0.f, 0.f, 0.f};
#pragma unroll
        for (int nt = 0; nt < 8; ++nt) {
            float cb = cb1f[nt * 16 + n15];
            float cw = cw2f[nt * 16 + n15];
#pragma unroll
            for (int r = 0; r < 4; ++r) php[r] += siluf(acc3[m][nt][r] + cb) * cw;
        }
#pragma unroll
        for (int mk = 1; mk < 16; mk <<= 1)
#pragma unroll
            for (int r = 0; r < 4; ++r) php[r] += __shfl_xor(php[r], mk);

        const int ebase = wb + m * 16;
        int er[4], ec[4];
        bool mk4[4];
#pragma unroll
        for (int r = 0; r < 4; ++r) {
            er[r] = __shfl(row_e[m], quad * 4 + r);
            ec[r] = __shfl(col_e[m], quad * 4 + r);
            mk4[r] = (ebase + quad * 4 + r) < E;
        }

        if (n15 == 0) {
#pragma unroll
            for (int r = 0; r < 4; ++r) {
                if (!mk4[r]) continue;
                float s = eij[m][r] * php[r];
#pragma unroll
                for (int d = 0; d < 3; ++d) {
                    float xd = ldf(x, er[r] * 3 + d, flag) - ldf(x, ec[r] * 3 + d, flag);
                    atomicAdd(&agg_x[er[r] * 3 + d], nz(s * xd));
                }
            }
        }

        if (CSR) {
            int p = 0;
            while (p < 16 && (ebase + p) < E) {
                int rowp = __shfl(row_e[m], p);
                unsigned bal = (unsigned)__ballot(row_e[m] == rowp) & 0xFFFFu;
                unsigned bits = (~bal) >> p;
                int q = p + __builtin_ctz(bits);
                float s[8];
#pragma unroll
                for (int nt = 0; nt < 8; ++nt) s[nt] = 0.f;
#pragma unroll
                for (int r = 0; r < 4; ++r) {
                    int idx = quad * 4 + r;
                    bool in = (idx >= p) && (idx < q) && ((ebase + idx) < E);
                    float w = in ? eij[m][r] : 0.f;
#pragma unroll
                    for (int nt = 0; nt < 8; ++nt) s[nt] += w * mv[m][nt][r];
                }
#pragma unroll
                for (int nt = 0; nt < 8; ++nt) {
                    s[nt] += __shfl_xor(s[nt], 16);
                    s[nt] += __shfl_xor(s[nt], 32);
                }
                if (quad == 0) {
#pragma unroll
                    for (int nt = 0; nt < 8; ++nt)
                        atomicAdd(&m_i[(size_t)rowp * 128 + nt * 16 + n15], nz(s[nt]));
                }
                p = q;
            }
        } else {
#pragma unroll
            for (int nt = 0; nt < 8; ++nt)
#pragma unroll
                for (int r = 0; r < 4; ++r)
                    if (mk4[r]) atomicAdd(&m_i[er[r] * 128 + nt * 16 + n15],
                                          nz(eij[m][r] * mv[m][nt][r]));
        }
    }
}

// ---------------------------------------------------------------------------
extern "C" void kernel_launch(void* const* d_in, const int* in_sizes, int n_in,
                              void* d_out, int out_size, void* d_ws, size_t ws_size,
                              hipStream_t stream) {
    const void* h = d_in[0];
    const void* x = d_in[1];
    const void* eattr = d_in[2];
    const void* v_init = d_in[3];
    const int* eidx = (const int*)d_in[4];

    const int N = in_sizes[0] / 128;
    const int E = in_sizes[4] / 2;
    const int* erow = eidx;
    const int* ecol = eidx + E;

    char* ws = (char*)d_ws;
    int* flag = (int*)ws;                       // 256
    short* W1t = (short*)(ws + 256);            // 73728
    short* W2t = (short*)(ws + 73984);          // 32768
    short* cW1t = (short*)(ws + 106752);        // 32768
    short* iW1t = (short*)(ws + 139520);        // 16384
    float* biasblk = (float*)(ws + 155904);     // 1412 floats -> pad to 162048
    short* nW1b = (short*)(ws + 162048);        // 65536
    short* nW2b = (short*)(ws + 227584);        // 32768
    short* vW1b = (short*)(ws + 260352);        // 32768
    int* bsum = (int*)(ws + 293120);            // 512
    int* bpre = (int*)(ws + 293632);            // 512
    short* hb = (short*)(ws + 294144);          // N*256
    size_t o = 294144 + (size_t)N * 256;
    // zero region: cnt + cur + agg_x + m_i (contiguous)
    size_t oZero = o;
    int* cnt = (int*)(ws + o); o += (size_t)N * 4;
    int* cur = (int*)(ws + o); o += (size_t)N * 4;
    float* agg_x = (float*)(ws + o); o += (size_t)N * 12;
    float* m_i = (float*)(ws + o); o += (size_t)N * 512;
    size_t zeroBytes = o - oZero;
    // CSR extras
    int* offp = (int*)(ws + o); o += (size_t)(N + 16) * 4;
    int* elist = (int*)(ws + o); o += (size_t)E * 4;
    const size_t need_csr = o;
    // precomputed h@W1 partials (bf16 N x 128 each)
    short* hA = (short*)(ws + o); o += (size_t)N * 256;
    short* hB = (short*)(ws + o); o += (size_t)N * 256;
    const size_t need_full = o;

    const bool csr = (ws_size >= need_csr);
    const bool pre = (ws_size >= need_full);

    detect_kernel<<<1, 64, 0, stream>>>((const unsigned int*)h, flag);

    const int prep_elems = 36864 + 16384 + 16384 + 8192 + 1412 + 32768 + 16384 + 16384;
    prep_kernel<<<(prep_elems + 255) / 256, 256, 0, stream>>>(
        d_in[5], d_in[7], d_in[9], d_in[12],
        d_in[6], d_in[8], d_in[10], d_in[11], d_in[13], d_in[14], d_in[15],
        d_in[17], d_in[19], d_in[21], d_in[22],
        d_in[16], d_in[18], d_in[20],
        W1t, W2t, cW1t, iW1t, biasblk, nW1b, nW2b, vW1b, flag);

    convh_kernel<<<(N * 128 + 255) / 256, 256, 0, stream>>>(h, hb, flag, N * 128);

    if (pre) {
        hw1_kernel<<<(N + 127) / 128, 256, 0, stream>>>(hb, W1t, hA, hB, N);
    }

    hipMemsetAsync((void*)(ws + oZero), 0, zeroBytes, stream);
    count_kernel<<<(E + 255) / 256, 256, 0, stream>>>(erow, cnt, E);

    if (csr) {
        const int nb = (N + 1023) / 1024;
        scan1_kernel<<<nb, 1024, 0, stream>>>(cnt, offp, bsum, N);
        scan2_kernel<<<1, 64, 0, stream>>>(bsum, bpre, nb);
        scan3_kernel<<<(N + 255) / 256, 256, 0, stream>>>(offp, bpre, N);
        fill_kernel<<<(E + 255) / 256, 256, 0, stream>>>(erow, offp, cur, elist, E);
    }

    if (pre && csr) {
        edge_kernel<true><<<(E + 63) / 64, 256, 0, stream>>>(
            hA, hB, x, eattr, erow, ecol, elist, W2t, cW1t, iW1t, biasblk,
            m_i, agg_x, E, flag);
    } else if (csr) {
        edge_kernel_old<true><<<(E + 127) / 128, 256, 0, stream>>>(
            hb, x, eattr, erow, ecol, elist, W1t, W2t, cW1t, iW1t, biasblk,
            m_i, agg_x, E, flag);
    } else {
        edge_kernel_old<false><<<(E + 127) / 128, 256, 0, stream>>>(
            hb, x, eattr, erow, ecol, nullptr, W1t, W2t, cW1t, iW1t, biasblk,
            m_i, agg_x, E, flag);
    }

    node_kernel<<<(N + 63) / 64, 256, 0, stream>>>(
        hb, x, v_init, cnt, m_i, agg_x,
        nW1b, nW2b, vW1b, biasblk, d_out, N, N * 128, N * 131,
        1.0f / (float)(N - 1), flag);
}

// Round 18
// 887.354 us; speedup vs baseline: 1.1919x; 1.1771x over previous
//
#include <hip/hip_runtime.h>
#include <hip/hip_bf16.h>

typedef __attribute__((ext_vector_type(8))) short short8;
typedef __attribute__((ext_vector_type(4))) float f32x4;
typedef __hip_bfloat16 bf16;

__device__ __forceinline__ short f2bs_rn(float f) {   // fast RNE bf16 pack
    unsigned u = __builtin_bit_cast(unsigned, f);
    u += 0x7FFF + ((u >> 16) & 1);
    return (short)(u >> 16);
}
__device__ __forceinline__ float bs2f(short s) {
    unsigned u = ((unsigned)(unsigned short)s) << 16;
    return __builtin_bit_cast(float, u);
}
__device__ __forceinline__ float ldf(const void* p, int i, int flag) {
    return flag ? bs2f(((const short*)p)[i]) : ((const float*)p)[i];
}
__device__ __forceinline__ short ldbits(const void* p, int i, int flag) {
    return flag ? ((const short*)p)[i] : f2bs_rn(((const float*)p)[i]);
}
__device__ __forceinline__ void stf(void* p, int i, float v, int flag) {
    if (flag) ((bf16*)p)[i] = __float2bfloat16(v);
    else ((float*)p)[i] = v;
}
__device__ __forceinline__ float nz(float v) { return (v == v) ? v : 0.f; }
__device__ __forceinline__ float siluf(float v) {
    return v * __builtin_amdgcn_rcpf(1.f + __expf(-v));
}
__device__ __forceinline__ float sigmf(float v) {
    return __builtin_amdgcn_rcpf(1.f + __expf(-v));
}

// ---------------------------------------------------------------------------
__global__ void detect_kernel(const unsigned int* __restrict__ hw, int* __restrict__ flag) {
    unsigned int w = hw[threadIdx.x];
    unsigned int e = (w >> 7) & 0xFF;
    bool ok = (e >= 113 && e <= 135);
    unsigned long long m = __ballot(ok);
    if (threadIdx.x == 0) *flag = (__popcll(m) >= 32) ? 1 : 0;
}

// ---------------------------------------------------------------------------
// prep: ALL weights in MFMA B-fragment order:
//   frag chunk c = kc*NT + nt, element r = lane*8 + j
//   -> W[k = kc*32 + (lane>>4)*8 + j][n = nt*16 + (lane&15)]
// biasblk extended with W1 rows 256 (dist) / 257 (attr) at 1156 / 1284.
// ---------------------------------------------------------------------------
__global__ void prep_kernel(
    const void* eW1, const void* eW2, const void* cW1, const void* iW1,
    const void* eb1, const void* eb2, const void* cb1, const void* cw2,
    const void* ib1, const void* iw2, const void* ib2, const void* nb1,
    const void* nb2, const void* vb1, const void* vW2,
    const void* nW1, const void* nW2, const void* vW1,
    short* __restrict__ W1t, short* __restrict__ W2t,
    short* __restrict__ cW1t, short* __restrict__ iW1t,
    float* __restrict__ biasblk, short* __restrict__ nW1b,
    short* __restrict__ nW2b, short* __restrict__ vW1b,
    const int* __restrict__ flagp) {
    const int flag = *flagp;
    int i = blockIdx.x * 256 + threadIdx.x;
    if (i < 36864) {  // W1 fragments: 9 kc x 8 nt x 512
        int c = i >> 9, r = i & 511;
        int kc = c >> 3, nt = c & 7;
        int ln = r >> 3, j = r & 7;
        int k = kc * 32 + ((ln >> 4) << 3) + j;
        int n = nt * 16 + (ln & 15);
        W1t[i] = (k < 258) ? ldbits(eW1, k * 128 + n, flag) : (short)0;
        return;
    }
    i -= 36864;
    if (i < 16384) {  // W2 fragments: 4 kc x 8 nt
        int c = i >> 9, r = i & 511;
        int kc = c >> 3, nt = c & 7;
        int ln = r >> 3, j = r & 7;
        int k = kc * 32 + ((ln >> 4) << 3) + j;
        int n = nt * 16 + (ln & 15);
        W2t[i] = ldbits(eW2, k * 128 + n, flag);
        return;
    }
    i -= 16384;
    if (i < 16384) {  // coord W1 fragments: 4 kc x 8 nt
        int c = i >> 9, r = i & 511;
        int kc = c >> 3, nt = c & 7;
        int ln = r >> 3, j = r & 7;
        int k = kc * 32 + ((ln >> 4) << 3) + j;
        int n = nt * 16 + (ln & 15);
        cW1t[i] = ldbits(cW1, k * 128 + n, flag);
        return;
    }
    i -= 16384;
    if (i < 8192) {  // inf W1 fragments: 4 kc x 4 nt
        int c = i >> 9, r = i & 511;
        int kc = c >> 2, nt = c & 3;
        int ln = r >> 3, j = r & 7;
        int k = kc * 32 + ((ln >> 4) << 3) + j;
        int n = nt * 16 + (ln & 15);
        iW1t[i] = ldbits(iW1, k * 64 + n, flag);
        return;
    }
    i -= 8192;
    if (i < 1412) {
        float v;
        if (i < 128) v = ldf(eb1, i, flag);
        else if (i < 256) v = ldf(eb2, i - 128, flag);
        else if (i < 384) v = ldf(cb1, i - 256, flag);
        else if (i < 512) v = ldf(cw2, i - 384, flag);
        else if (i < 576) v = ldf(ib1, i - 512, flag);
        else if (i < 640) v = ldf(iw2, i - 576, flag);
        else if (i < 644) v = (i == 640) ? ldf(ib2, 0, flag) : 0.f;
        else if (i < 772) v = ldf(nb1, i - 644, flag);
        else if (i < 900) v = ldf(nb2, i - 772, flag);
        else if (i < 1028) v = ldf(vb1, i - 900, flag);
        else if (i < 1156) v = ldf(vW2, i - 1028, flag);
        else if (i < 1284) v = ldf(eW1, 256 * 128 + (i - 1156), flag);  // dist row
        else v = ldf(eW1, 257 * 128 + (i - 1284), flag);                // attr row
        biasblk[i] = v;
        return;
    }
    i -= 1412;
    if (i < 32768) {  // node W1 fragments: 8 kc x 8 nt
        int c = i >> 9, r = i & 511;
        int kc = c >> 3, nt = c & 7;
        int ln = r >> 3, j = r & 7;
        int k = kc * 32 + ((ln >> 4) << 3) + j;
        int n = nt * 16 + (ln & 15);
        nW1b[i] = ldbits(nW1, k * 128 + n, flag);
        return;
    }
    i -= 32768;
    if (i < 16384) {  // node W2 fragments: 4 kc x 8 nt
        int c = i >> 9, r = i & 511;
        int kc = c >> 3, nt = c & 7;
        int ln = r >> 3, j = r & 7;
        int k = kc * 32 + ((ln >> 4) << 3) + j;
        int n = nt * 16 + (ln & 15);
        nW2b[i] = ldbits(nW2, k * 128 + n, flag);
        return;
    }
    i -= 16384;
    if (i < 16384) {  // vel W1 fragments: 4 kc x 8 nt
        int c = i >> 9, r = i & 511;
        int kc = c >> 3, nt = c & 7;
        int ln = r >> 3, j = r & 7;
        int k = kc * 32 + ((ln >> 4) << 3) + j;
        int n = nt * 16 + (ln & 15);
        vW1b[i] = ldbits(vW1, k * 128 + n, flag);
    }
}

// ---------------------------------------------------------------------------
__global__ void convh_kernel(const void* __restrict__ h, short* __restrict__ hb,
                             const int* __restrict__ flagp, int n) {
    const int flag = *flagp;
    int i = blockIdx.x * 256 + threadIdx.x;
    if (i < n) hb[i] = ldbits(h, i, flag);
}

// ---------------------------------------------------------------------------
// hw1: precompute hA = h @ W1[0:128], hB = h @ W1[128:256] (bf16, N x 128).
// ---------------------------------------------------------------------------
__global__ __launch_bounds__(256) void hw1_kernel(
    const short* __restrict__ hb, const short* __restrict__ W1t,
    short* __restrict__ hA, short* __restrict__ hB, int N) {
    const int tid = threadIdx.x;
    const int wv = tid >> 6;
    const int lane = tid & 63;
    const int n15 = lane & 15;
    const int quad = lane >> 4;
    const int base = blockIdx.x * 128 + wv * 32;

    f32x4 accA[2][8], accB[2][8];
#pragma unroll
    for (int m = 0; m < 2; ++m)
#pragma unroll
        for (int nt = 0; nt < 8; ++nt) {
            accA[m][nt] = (f32x4){0.f, 0.f, 0.f, 0.f};
            accB[m][nt] = (f32x4){0.f, 0.f, 0.f, 0.f};
        }

#pragma unroll
    for (int kc = 0; kc < 4; ++kc) {
        short8 a[2];
#pragma unroll
        for (int m = 0; m < 2; ++m) {
            int node = base + m * 16 + n15;
            if (node >= N) node = N - 1;
            a[m] = *(const short8*)(hb + node * 128 + kc * 32 + quad * 8);
        }
        const short* bpA = W1t + (kc * 8) * 512 + lane * 8;
        const short* bpB = W1t + ((kc + 4) * 8) * 512 + lane * 8;
#pragma unroll
        for (int nt = 0; nt < 8; ++nt) {
            short8 ba = *(const short8*)(bpA + nt * 512);
            short8 bb = *(const short8*)(bpB + nt * 512);
            accA[0][nt] = __builtin_amdgcn_mfma_f32_16x16x32_bf16(a[0], ba, accA[0][nt], 0, 0, 0);
            accA[1][nt] = __builtin_amdgcn_mfma_f32_16x16x32_bf16(a[1], ba, accA[1][nt], 0, 0, 0);
            accB[0][nt] = __builtin_amdgcn_mfma_f32_16x16x32_bf16(a[0], bb, accB[0][nt], 0, 0, 0);
            accB[1][nt] = __builtin_amdgcn_mfma_f32_16x16x32_bf16(a[1], bb, accB[1][nt], 0, 0, 0);
        }
    }

#pragma unroll
    for (int m = 0; m < 2; ++m)
#pragma unroll
        for (int nt = 0; nt < 8; ++nt)
#pragma unroll
            for (int r = 0; r < 4; ++r) {
                int node = base + m * 16 + quad * 4 + r;
                if (node < N) {
                    hA[node * 128 + nt * 16 + n15] = f2bs_rn(accA[m][nt][r]);
                    hB[node * 128 + nt * 16 + n15] = f2bs_rn(accB[m][nt][r]);
                }
            }
}

// ---------------------------------------------------------------------------
// CSR build
// ---------------------------------------------------------------------------
__global__ void count_kernel(const int* __restrict__ erow, int* __restrict__ cnt, int E) {
    int i = blockIdx.x * 256 + threadIdx.x;
    if (i < E) atomicAdd(&cnt[erow[i]], 1);
}

__global__ __launch_bounds__(1024) void scan1_kernel(const int* __restrict__ cnt,
                                                     int* __restrict__ off,
                                                     int* __restrict__ bsum, int N) {
    __shared__ int sm[1024];
    int t = threadIdx.x, i = blockIdx.x * 1024 + t;
    int c = (i < N) ? cnt[i] : 0;
    sm[t] = c;
    __syncthreads();
    for (int d = 1; d < 1024; d <<= 1) {
        int v = (t >= d) ? sm[t - d] : 0;
        __syncthreads();
        sm[t] += v;
        __syncthreads();
    }
    if (i < N) off[i] = sm[t] - c;
    if (t == 1023) bsum[blockIdx.x] = sm[1023];
}
__global__ void scan2_kernel(const int* __restrict__ bsum, int* __restrict__ bpre, int nb) {
    if (threadIdx.x == 0) {
        int run = 0;
        for (int b = 0; b < nb; ++b) { bpre[b] = run; run += bsum[b]; }
    }
}
__global__ void scan3_kernel(int* __restrict__ off, const int* __restrict__ bpre, int N) {
    int i = blockIdx.x * 256 + threadIdx.x;
    if (i < N) off[i] += bpre[i >> 10];
}
__global__ void fill_kernel(const int* __restrict__ erow, const int* __restrict__ off,
                            int* __restrict__ cur, int* __restrict__ elist, int E) {
    int i = blockIdx.x * 256 + threadIdx.x;
    if (i < E) {
        int r = erow[i];
        int p = off[r] + atomicAdd(&cur[r], 1);
        elist[p] = i;
    }
}

// ---------------------------------------------------------------------------
// edge kernel (PRE path): 4 waves x 16 edges, one m-tile per wave.
// (256,4) with hidden1 via the LDS tile: the exact configuration measured
// at edge 573us / total 903us, PASSED all checks incl. post-timing replay
// (round 10, same container class). Proven-stable final state.
// XCD swizzle + merged agg_x/m_i segment reduction.
// ---------------------------------------------------------------------------
template <bool CSR>
__global__ __launch_bounds__(256, 4) void edge_kernel(
    const short* __restrict__ hA, const short* __restrict__ hB,
    const void* __restrict__ x, const void* __restrict__ eattr,
    const int* __restrict__ erow, const int* __restrict__ ecol,
    const int* __restrict__ elist,
    const short* __restrict__ W2f, const short* __restrict__ cW1f,
    const short* __restrict__ iW1f,
    const float* __restrict__ biasblk,
    float* __restrict__ m_i, float* __restrict__ agg_x, int E,
    const int* __restrict__ flagp) {
    const int flag = *flagp;
    __shared__ __align__(16) short tiles[4][16 * 136];  // 17408 B
    const float* b1f = biasblk;
    const float* b2f = biasblk + 128;
    const float* cb1f = biasblk + 256;
    const float* cw2f = biasblk + 384;
    const float* ib1f = biasblk + 512;
    const float* iw2f = biasblk + 576;
    const float ib2s = biasblk[640];
    const float* w1df = biasblk + 1156;
    const float* w1af = biasblk + 1284;

    // bijective chunked XCD swizzle (m204): consecutive CSR tiles -> same XCD.
    int bid;
    {
        const int nwg = gridDim.x;
        const int qq = nwg >> 3, r8 = nwg & 7;
        const int xcd = blockIdx.x & 7, idx = blockIdx.x >> 3;
        const int base = (xcd < r8) ? xcd * (qq + 1) : r8 * (qq + 1) + (xcd - r8) * qq;
        bid = base + idx;
    }

    const int tid = threadIdx.x;
    const int wv = tid >> 6;
    const int lane = tid & 63;
    const int n15 = lane & 15;
    const int quad = lane >> 4;
    const int wb = bid * 64 + wv * 16;

    int row_e, col_e;
    float dist, attr;
    {
        int slot = wb + n15;
        int sL = (slot < E) ? slot : (E - 1);
        int eL = CSR ? elist[sL] : sL;
        row_e = erow[eL];
        col_e = ecol[eL];
        float d = 0.f;
#pragma unroll
        for (int dd = 0; dd < 3; ++dd) {
            float xd = ldf(x, row_e * 3 + dd, flag) - ldf(x, col_e * 3 + dd, flag);
            d += xd * xd;
        }
        dist = d;
        attr = ldf(eattr, eL, flag);
    }

    // ---- col partial gather (random, L3 latency): 16 VGPR
    short8 cB[4];
#pragma unroll
    for (int c = 0; c < 4; ++c)
        cB[c] = *(const short8*)(hB + col_e * 128 + c * 32 + quad * 8);

    // ---- m1 = hA[row] + hB[col] + dist*W1d + attr*W1at + b1 -> silu -> tile
    short* tl = tiles[wv];
#pragma unroll
    for (int c = 0; c < 4; ++c) {
        short8 ra = *(const short8*)(hA + row_e * 128 + c * 32 + quad * 8);
        short8 ov;
#pragma unroll
        for (int j = 0; j < 8; ++j) {
            int f = c * 32 + quad * 8 + j;
            float v = bs2f(ra[j]) + bs2f(cB[c][j])
                    + dist * w1df[f] + attr * w1af[f] + b1f[f];
            ov[j] = f2bs_rn(siluf(v));
        }
        *(short8*)(tl + n15 * 136 + c * 32 + quad * 8) = ov;
    }

    // ---- GEMM2: hidden1 @ W2
    f32x4 acc2[8];
#pragma unroll
    for (int nt = 0; nt < 8; ++nt) acc2[nt] = (f32x4){0.f, 0.f, 0.f, 0.f};
#pragma unroll
    for (int kc = 0; kc < 4; ++kc) {
        short8 a = *(const short8*)(tl + n15 * 136 + kc * 32 + quad * 8);
        const short* bp = W2f + (kc * 8) * 512 + lane * 8;
#pragma unroll
        for (int nt = 0; nt < 8; ++nt) {
            short8 b = *(const short8*)(bp + nt * 512);
            acc2[nt] = __builtin_amdgcn_mfma_f32_16x16x32_bf16(a, b, acc2[nt], 0, 0, 0);
        }
    }

    // mv (bf16) goes ONLY to LDS; no register copy kept.
#pragma unroll
    for (int nt = 0; nt < 8; ++nt) {
        float bv = b2f[nt * 16 + n15];
#pragma unroll
        for (int r = 0; r < 4; ++r)
            tl[(quad * 4 + r) * 136 + nt * 16 + n15] = f2bs_rn(siluf(acc2[nt][r] + bv));
    }

    // ---- GEMM4 (inf, 64 cols) -> eij
    f32x4 acc4[4];
#pragma unroll
    for (int nt = 0; nt < 4; ++nt) acc4[nt] = (f32x4){0.f, 0.f, 0.f, 0.f};
#pragma unroll
    for (int kc = 0; kc < 4; ++kc) {
        short8 a = *(const short8*)(tl + n15 * 136 + kc * 32 + quad * 8);
        const short* bp = iW1f + (kc * 4) * 512 + lane * 8;
#pragma unroll
        for (int nt = 0; nt < 4; ++nt) {
            short8 b = *(const short8*)(bp + nt * 512);
            acc4[nt] = __builtin_amdgcn_mfma_f32_16x16x32_bf16(a, b, acc4[nt], 0, 0, 0);
        }
    }
    float eij[4];
    {
        float inp[4] = {0.f, 0.f, 0.f, 0.f};
#pragma unroll
        for (int nt = 0; nt < 4; ++nt) {
            float ib = ib1f[nt * 16 + n15];
            float iw = iw2f[nt * 16 + n15];
#pragma unroll
            for (int r = 0; r < 4; ++r) inp[r] += siluf(acc4[nt][r] + ib) * iw;
        }
#pragma unroll
        for (int mk = 1; mk < 16; mk <<= 1)
#pragma unroll
            for (int r = 0; r < 4; ++r) inp[r] += __shfl_xor(inp[r], mk);
#pragma unroll
        for (int r = 0; r < 4; ++r) eij[r] = sigmf(inp[r] + ib2s);
    }

    // ---- GEMM3 (coord) -> phi
    f32x4 acc3[8];
#pragma unroll
    for (int nt = 0; nt < 8; ++nt) acc3[nt] = (f32x4){0.f, 0.f, 0.f, 0.f};
#pragma unroll
    for (int kc = 0; kc < 4; ++kc) {
        short8 a = *(const short8*)(tl + n15 * 136 + kc * 32 + quad * 8);
        const short* bp = cW1f + (kc * 8) * 512 + lane * 8;
#pragma unroll
        for (int nt = 0; nt < 8; ++nt) {
            short8 b = *(const short8*)(bp + nt * 512);
            acc3[nt] = __builtin_amdgcn_mfma_f32_16x16x32_bf16(a, b, acc3[nt], 0, 0, 0);
        }
    }

    // ---- epilogue + aggregation
    {
        float php[4] = {0.f, 0.f, 0.f, 0.f};
#pragma unroll
        for (int nt = 0; nt < 8; ++nt) {
            float cb = cb1f[nt * 16 + n15];
            float cw = cw2f[nt * 16 + n15];
#pragma unroll
            for (int r = 0; r < 4; ++r) php[r] += siluf(acc3[nt][r] + cb) * cw;
        }
#pragma unroll
        for (int mk = 1; mk < 16; mk <<= 1)
#pragma unroll
            for (int r = 0; r < 4; ++r) php[r] += __shfl_xor(php[r], mk);
        // php[r]/eij[r] now uniform across n15 within each quad

        // distribute per-edge s = eij*php to the lane owning edge n15:
        // source quad = n15>>2, slot r = n15&3
        float sv[4];
#pragma unroll
        for (int r = 0; r < 4; ++r) sv[r] = eij[r] * php[r];
        const int srcl = (n15 >> 2) * 16;
        float t0 = __shfl(sv[0], srcl);
        float t1 = __shfl(sv[1], srcl);
        float t2 = __shfl(sv[2], srcl);
        float t3 = __shfl(sv[3], srcl);
        const int rr = n15 & 3;
        float s_e = (rr == 0) ? t0 : (rr == 1) ? t1 : (rr == 2) ? t2 : t3;

        // per-lane dim contribution: quad = dim (quad 3 idle)
        float val = 0.f;
        if (quad < 3) {
            float xd = ldf(x, row_e * 3 + quad, flag) - ldf(x, col_e * 3 + quad, flag);
            val = ((wb + n15) < E) ? nz(s_e * xd) : 0.f;
        }

        const int ebase = wb;
        if (CSR) {
            // merged segment loop: m_i (LDS mv) + agg_x, one atomic set per row
            int p = 0;
            while (p < 16 && (ebase + p) < E) {
                int rowp = __shfl(row_e, p);
                unsigned bal = (unsigned)__ballot(row_e == rowp) & 0xFFFFu;
                unsigned bits = (~bal) >> p;  // bit16 of ~bal is set -> bounded
                int q = p + __builtin_ctz(bits);

                // agg_x: sum val over n15 in [p,q) within each quad (dim)
                float av = (n15 >= p && n15 < q) ? val : 0.f;
#pragma unroll
                for (int mk = 1; mk < 16; mk <<= 1) av += __shfl_xor(av, mk);
                if (n15 == 0 && quad < 3) atomicAdd(&agg_x[rowp * 3 + quad], av);

                // m_i: weighted sum of LDS mv rows
                float s[8];
#pragma unroll
                for (int nt = 0; nt < 8; ++nt) s[nt] = 0.f;
#pragma unroll
                for (int r = 0; r < 4; ++r) {
                    int idx = quad * 4 + r;
                    bool in = (idx >= p) && (idx < q) && ((ebase + idx) < E);
                    float w = in ? eij[r] : 0.f;
#pragma unroll
                    for (int nt = 0; nt < 8; ++nt)
                        s[nt] += w * bs2f(tl[idx * 136 + nt * 16 + n15]);
                }
#pragma unroll
                for (int nt = 0; nt < 8; ++nt) {
                    s[nt] += __shfl_xor(s[nt], 16);
                    s[nt] += __shfl_xor(s[nt], 32);
                }
                if (quad == 0) {
#pragma unroll
                    for (int nt = 0; nt < 8; ++nt)
                        atomicAdd(&m_i[(size_t)rowp * 128 + nt * 16 + n15], nz(s[nt]));
                }
                p = q;
            }
        } else {
            // per-edge fallback (rows unsorted): lane-parallel agg_x
            if (quad < 3 && (wb + n15) < E)
                atomicAdd(&agg_x[row_e * 3 + quad], val);
#pragma unroll
            for (int nt = 0; nt < 8; ++nt)
#pragma unroll
                for (int r = 0; r < 4; ++r) {
                    int idx = quad * 4 + r;
                    if ((ebase + idx) < E) {
                        int er = __shfl(row_e, idx);
                        atomicAdd(&m_i[er * 128 + nt * 16 + n15],
                                  nz(eij[r] * bs2f(tl[idx * 136 + nt * 16 + n15])));
                    }
                }
        }
    }
}

// ---------------------------------------------------------------------------
// node kernel (MFMA): round-9 proven version, unchanged.
// ---------------------------------------------------------------------------
__global__ __launch_bounds__(256, 4) void node_kernel(
    const short* __restrict__ hb, const void* __restrict__ x,
    const void* __restrict__ v_init,
    const int* __restrict__ cnt,
    const float* __restrict__ m_i, const float* __restrict__ agg_x,
    const short* __restrict__ nW1f, const short* __restrict__ nW2f,
    const short* __restrict__ vW1f, const float* __restrict__ biasblk,
    void* __restrict__ out, int N, int xbase, int vbase, float inv_nm1,
    const int* __restrict__ flagp) {
    const int flag = *flagp;
    __shared__ __align__(16) short tiles[4][16 * 136];  // 17408 B
    const float* nb1f = biasblk + 644;
    const float* nb2f = biasblk + 772;
    const float* vb1f = biasblk + 900;
    const float* vW2f = biasblk + 1028;

    const int tid = threadIdx.x;
    const int wv = tid >> 6;
    const int lane = tid & 63;
    const int n15 = lane & 15;
    const int quad = lane >> 4;
    const int base = blockIdx.x * 64 + wv * 16;

    short* tl = tiles[wv];

    // ---- stage m_i (bf16 + nz) into tile: row n15, col c*32+quad*8..+8
    {
        int node = base + n15;
        if (node >= N) node = N - 1;
#pragma unroll
        for (int c = 0; c < 4; ++c) {
            const float* mp = m_i + (size_t)node * 128 + c * 32 + quad * 8;
            short8 ov;
#pragma unroll
            for (int j = 0; j < 8; ++j) ov[j] = f2bs_rn(nz(mp[j]));
            *(short8*)(tl + n15 * 136 + c * 32 + quad * 8) = ov;
        }
    }
    int anode = base + n15;
    if (anode >= N) anode = N - 1;

    // ---- vel GEMM: h @ vW1 -> silu -> * vW2 -> row-reduce -> vscale
    f32x4 acc[8];
#pragma unroll
    for (int nt = 0; nt < 8; ++nt) acc[nt] = (f32x4){0.f, 0.f, 0.f, 0.f};
#pragma unroll
    for (int kc = 0; kc < 4; ++kc) {
        short8 a = *(const short8*)(hb + (size_t)anode * 128 + kc * 32 + quad * 8);
        const short* bp = vW1f + (kc * 8) * 512 + lane * 8;
#pragma unroll
        for (int nt = 0; nt < 8; ++nt) {
            short8 b = *(const short8*)(bp + nt * 512);
            acc[nt] = __builtin_amdgcn_mfma_f32_16x16x32_bf16(a, b, acc[nt], 0, 0, 0);
        }
    }
    float vsc[4] = {0.f, 0.f, 0.f, 0.f};
#pragma unroll
    for (int nt = 0; nt < 8; ++nt) {
        int j = nt * 16 + n15;
        float vb = vb1f[j];
        float vw = vW2f[j];
#pragma unroll
        for (int r = 0; r < 4; ++r) vsc[r] += siluf(acc[nt][r] + vb) * vw;
    }
#pragma unroll
    for (int mk = 1; mk < 16; mk <<= 1)
#pragma unroll
        for (int r = 0; r < 4; ++r) vsc[r] += __shfl_xor(vsc[r], mk);

    // ---- node GEMM1: [h | m_i] @ nW1 -> silu -> tile
#pragma unroll
    for (int nt = 0; nt < 8; ++nt) acc[nt] = (f32x4){0.f, 0.f, 0.f, 0.f};
#pragma unroll
    for (int kc = 0; kc < 8; ++kc) {
        short8 a;
        if (kc < 4) a = *(const short8*)(hb + (size_t)anode * 128 + kc * 32 + quad * 8);
        else        a = *(const short8*)(tl + n15 * 136 + (kc - 4) * 32 + quad * 8);
        const short* bp = nW1f + (kc * 8) * 512 + lane * 8;
#pragma unroll
        for (int nt = 0; nt < 8; ++nt) {
            short8 b = *(const short8*)(bp + nt * 512);
            acc[nt] = __builtin_amdgcn_mfma_f32_16x16x32_bf16(a, b, acc[nt], 0, 0, 0);
        }
    }
#pragma unroll
    for (int nt = 0; nt < 8; ++nt) {
        float bv = nb1f[nt * 16 + n15];
#pragma unroll
        for (int r = 0; r < 4; ++r)
            tl[(quad * 4 + r) * 136 + nt * 16 + n15] = f2bs_rn(siluf(acc[nt][r] + bv));
    }

    // ---- node GEMM2: hidden @ nW2 -> out
#pragma unroll
    for (int nt = 0; nt < 8; ++nt) acc[nt] = (f32x4){0.f, 0.f, 0.f, 0.f};
#pragma unroll
    for (int kc = 0; kc < 4; ++kc) {
        short8 a = *(const short8*)(tl + n15 * 136 + kc * 32 + quad * 8);
        const short* bp = nW2f + (kc * 8) * 512 + lane * 8;
#pragma unroll
        for (int nt = 0; nt < 8; ++nt) {
            short8 b = *(const short8*)(bp + nt * 512);
            acc[nt] = __builtin_amdgcn_mfma_f32_16x16x32_bf16(a, b, acc[nt], 0, 0, 0);
        }
    }
#pragma unroll
    for (int nt = 0; nt < 8; ++nt) {
        float bv = nb2f[nt * 16 + n15];
#pragma unroll
        for (int r = 0; r < 4; ++r) {
            int node = base + quad * 4 + r;
            if (node < N) stf(out, node * 128 + nt * 16 + n15, nz(acc[nt][r] + bv), flag);
        }
    }

    // ---- x / v outputs (3 dims per node; lanes n15<3 of each quad)
    if (n15 < 3) {
#pragma unroll
        for (int r = 0; r < 4; ++r) {
            int node = base + quad * 4 + r;
            if (node >= N) continue;
            int d = n15;
            float vj = nz(ldf(v_init, node * 3 + d, flag) * vsc[r]);
            stf(out, vbase + node * 3 + d, vj, flag);
            float xv = ldf(x, node * 3 + d, flag);
            float xo = (cnt[node] > 0) ? xv + vj + nz(agg_x[node * 3 + d]) * inv_nm1 : xv;
            stf(out, xbase + node * 3 + d, nz(xo), flag);
        }
    }
}

// ---------------------------------------------------------------------------
// legacy edge kernel (round-2 exact): used only when workspace too small.
// ---------------------------------------------------------------------------
template <bool CSR>
__global__ __launch_bounds__(256, 2) void edge_kernel_old(
    const short* __restrict__ hb, const void* __restrict__ x,
    const void* __restrict__ eattr,
    const int* __restrict__ erow, const int* __restrict__ ecol,
    const int* __restrict__ elist,
    const short* __restrict__ W1f, const short* __restrict__ W2f,
    const short* __restrict__ cW1f, const short* __restrict__ iW1f,
    const float* __restrict__ biasblk,
    float* __restrict__ m_i, float* __restrict__ agg_x, int E,
    const int* __restrict__ flagp) {
    const int flag = *flagp;
    __shared__ __align__(16) short tiles[8][16 * 136];
    const float* b1f = biasblk;
    const float* b2f = biasblk + 128;
    const float* cb1f = biasblk + 256;
    const float* cw2f = biasblk + 384;
    const float* ib1f = biasblk + 512;
    const float* iw2f = biasblk + 576;
    const float ib2s = biasblk[640];

    const int tid = threadIdx.x;
    const int wv = tid >> 6;
    const int lane = tid & 63;
    const int n15 = lane & 15;
    const int quad = lane >> 4;
    const int wb = blockIdx.x * 128 + wv * 32;

    int row_e[2], col_e[2];
    float dist[2], attr[2];
#pragma unroll
    for (int m = 0; m < 2; ++m) {
        int slot = wb + m * 16 + n15;
        int sL = (slot < E) ? slot : (E - 1);
        int eL = CSR ? elist[sL] : sL;
        row_e[m] = erow[eL];
        col_e[m] = ecol[eL];
        float d = 0.f;
#pragma unroll
        for (int dd = 0; dd < 3; ++dd) {
            float xd = ldf(x, row_e[m] * 3 + dd, flag) - ldf(x, col_e[m] * 3 + dd, flag);
            d += xd * xd;
        }
        dist[m] = d;
        attr[m] = ldf(eattr, eL, flag);
    }

    short8 cA[2][4];
#pragma unroll
    for (int m = 0; m < 2; ++m)
#pragma unroll
        for (int c = 0; c < 4; ++c)
            cA[m][c] = *(const short8*)(hb + col_e[m] * 128 + c * 32 + quad * 8);

    f32x4 acc1[2][8];
#pragma unroll
    for (int m = 0; m < 2; ++m)
#pragma unroll
        for (int nt = 0; nt < 8; ++nt) acc1[m][nt] = (f32x4){0.f, 0.f, 0.f, 0.f};

#pragma unroll
    for (int kc = 0; kc < 9; ++kc) {
        short8 a[2];
        if (kc < 4) {
            a[0] = *(const short8*)(hb + row_e[0] * 128 + kc * 32 + quad * 8);
            a[1] = *(const short8*)(hb + row_e[1] * 128 + kc * 32 + quad * 8);
        } else if (kc < 8) {
            a[0] = cA[0][kc - 4];
            a[1] = cA[1][kc - 4];
        } else {
#pragma unroll
            for (int m = 0; m < 2; ++m) {
#pragma unroll
                for (int t = 0; t < 8; ++t) a[m][t] = 0;
                if (quad == 0) { a[m][0] = f2bs_rn(dist[m]); a[m][1] = f2bs_rn(attr[m]); }
            }
        }
        const short* bp = W1f + (kc * 8) * 512 + lane * 8;
#pragma unroll
        for (int nt = 0; nt < 8; ++nt) {
            short8 b = *(const short8*)(bp + nt * 512);
            acc1[0][nt] = __builtin_amdgcn_mfma_f32_16x16x32_bf16(a[0], b, acc1[0][nt], 0, 0, 0);
            acc1[1][nt] = __builtin_amdgcn_mfma_f32_16x16x32_bf16(a[1], b, acc1[1][nt], 0, 0, 0);
        }
    }

#pragma unroll
    for (int m = 0; m < 2; ++m) {
        short* tl = tiles[wv * 2 + m];
#pragma unroll
        for (int nt = 0; nt < 8; ++nt) {
            float bv = b1f[nt * 16 + n15];
#pragma unroll
            for (int r = 0; r < 4; ++r)
                tl[(quad * 4 + r) * 136 + nt * 16 + n15] = f2bs_rn(siluf(acc1[m][nt][r] + bv));
        }
    }

    f32x4 acc2[2][8];
#pragma unroll
    for (int m = 0; m < 2; ++m)
#pragma unroll
        for (int nt = 0; nt < 8; ++nt) acc2[m][nt] = (f32x4){0.f, 0.f, 0.f, 0.f};
#pragma unroll
    for (int kc = 0; kc < 4; ++kc) {
        short8 a[2];
#pragma unroll
        for (int m = 0; m < 2; ++m)
            a[m] = *(const short8*)(tiles[wv * 2 + m] + n15 * 136 + kc * 32 + quad * 8);
        const short* bp = W2f + (kc * 8) * 512 + lane * 8;
#pragma unroll
        for (int nt = 0; nt < 8; ++nt) {
            short8 b = *(const short8*)(bp + nt * 512);
            acc2[0][nt] = __builtin_amdgcn_mfma_f32_16x16x32_bf16(a[0], b, acc2[0][nt], 0, 0, 0);
            acc2[1][nt] = __builtin_amdgcn_mfma_f32_16x16x32_bf16(a[1], b, acc2[1][nt], 0, 0, 0);
        }
    }

    float mv[2][8][4];
#pragma unroll
    for (int m = 0; m < 2; ++m) {
        short* tl = tiles[wv * 2 + m];
#pragma unroll
        for (int nt = 0; nt < 8; ++nt) {
            float bv = b2f[nt * 16 + n15];
#pragma unroll
            for (int r = 0; r < 4; ++r) {
                float v = siluf(acc2[m][nt][r] + bv);
                mv[m][nt][r] = v;
                tl[(quad * 4 + r) * 136 + nt * 16 + n15] = f2bs_rn(v);
            }
        }
    }

    f32x4 acc4[2][4];
#pragma unroll
    for (int m = 0; m < 2; ++m)
#pragma unroll
        for (int nt = 0; nt < 4; ++nt) acc4[m][nt] = (f32x4){0.f, 0.f, 0.f, 0.f};
#pragma unroll
    for (int kc = 0; kc < 4; ++kc) {
        short8 a[2];
#pragma unroll
        for (int m = 0; m < 2; ++m)
            a[m] = *(const short8*)(tiles[wv * 2 + m] + n15 * 136 + kc * 32 + quad * 8);
        const short* bp = iW1f + (kc * 4) * 512 + lane * 8;
#pragma unroll
        for (int nt = 0; nt < 4; ++nt) {
            short8 b = *(const short8*)(bp + nt * 512);
            acc4[0][nt] = __builtin_amdgcn_mfma_f32_16x16x32_bf16(a[0], b, acc4[0][nt], 0, 0, 0);
            acc4[1][nt] = __builtin_amdgcn_mfma_f32_16x16x32_bf16(a[1], b, acc4[1][nt], 0, 0, 0);
        }
    }
    float eij[2][4];
#pragma unroll
    for (int m = 0; m < 2; ++m) {
        float inp[4] = {0.f, 0.f, 0.f, 0.f};
#pragma unroll
        for (int nt = 0; nt < 4; ++nt) {
            float ib = ib1f[nt * 16 + n15];
            float iw = iw2f[nt * 16 + n15];
#pragma unroll
            for (int r = 0; r < 4; ++r) inp[r] += siluf(acc4[m][nt][r] + ib) * iw;
        }
#pragma unroll
        for (int mk = 1; mk < 16; mk <<= 1)
#pragma unroll
            for (int r = 0; r < 4; ++r) inp[r] += __shfl_xor(inp[r], mk);
#pragma unroll
        for (int r = 0; r < 4; ++r) eij[m][r] = sigmf(inp[r] + ib2s);
    }

    f32x4 acc3[2][8];
#pragma unroll
    for (int m = 0; m < 2; ++m)
#pragma unroll
        for (int nt = 0; nt < 8; ++nt) acc3[m][nt] = (f32x4){0.f, 0.f, 0.f, 0.f};
#pragma unroll
    for (int kc = 0; kc < 4; ++kc) {
        short8 a[2];
#pragma unroll
        for (int m = 0; m < 2; ++m)
            a[m] = *(const short8*)(tiles[wv * 2 + m] + n15 * 136 + kc * 32 + quad * 8);
        const short* bp = cW1f + (kc * 8) * 512 + lane * 8;
#pragma unroll
        for (int nt = 0; nt < 8; ++nt) {
            short8 b = *(const short8*)(bp + nt * 512);
            acc3[0][nt] = __builtin_amdgcn_mfma_f32_16x16x32_bf16(a[0], b, acc3[0][nt], 0, 0, 0);
            acc3[1][nt] = __builtin_amdgcn_mfma_f32_16x16x32_bf16(a[1], b, acc3[1][nt], 0, 0, 0);
        }
    }

#pragma unroll
    for (int m = 0; m < 2; ++m) {
        float php[4] = {0.f, 0.f, 0.f, 0.f};
#pragma unroll
        for (int nt = 0; nt < 8; ++nt) {
            float cb = cb1f[nt * 16 + n15];
            float cw = cw2f[nt * 16 + n15];
#pragma unroll
            for (int r = 0; r < 4; ++r) php[r] += siluf(acc3[m][nt][r] + cb) * cw;
        }
#pragma unroll
        for (int mk = 1; mk < 16; mk <<= 1)
#pragma unroll
            for (int r = 0; r < 4; ++r) php[r] += __shfl_xor(php[r], mk);

        const int ebase = wb + m * 16;
        int er[4], ec[4];
        bool mk4[4];
#pragma unroll
        for (int r = 0; r < 4; ++r) {
            er[r] = __shfl(row_e[m], quad * 4 + r);
            ec[r] = __shfl(col_e[m], quad * 4 + r);
            mk4[r] = (ebase + quad * 4 + r) < E;
        }

        if (n15 == 0) {
#pragma unroll
            for (int r = 0; r < 4; ++r) {
                if (!mk4[r]) continue;
                float s = eij[m][r] * php[r];
#pragma unroll
                for (int d = 0; d < 3; ++d) {
                    float xd = ldf(x, er[r] * 3 + d, flag) - ldf(x, ec[r] * 3 + d, flag);
                    atomicAdd(&agg_x[er[r] * 3 + d], nz(s * xd));
                }
            }
        }

        if (CSR) {
            int p = 0;
            while (p < 16 && (ebase + p) < E) {
                int rowp = __shfl(row_e[m], p);
                unsigned bal = (unsigned)__ballot(row_e[m] == rowp) & 0xFFFFu;
                unsigned bits = (~bal) >> p;
                int q = p + __builtin_ctz(bits);
                float s[8];
#pragma unroll
                for (int nt = 0; nt < 8; ++nt) s[nt] = 0.f;
#pragma unroll
                for (int r = 0; r < 4; ++r) {
                    int idx = quad * 4 + r;
                    bool in = (idx >= p) && (idx < q) && ((ebase + idx) < E);
                    float w = in ? eij[m][r] : 0.f;
#pragma unroll
                    for (int nt = 0; nt < 8; ++nt) s[nt] += w * mv[m][nt][r];
                }
#pragma unroll
                for (int nt = 0; nt < 8; ++nt) {
                    s[nt] += __shfl_xor(s[nt], 16);
                    s[nt] += __shfl_xor(s[nt], 32);
                }
                if (quad == 0) {
#pragma unroll
                    for (int nt = 0; nt < 8; ++nt)
                        atomicAdd(&m_i[(size_t)rowp * 128 + nt * 16 + n15], nz(s[nt]));
                }
                p = q;
            }
        } else {
#pragma unroll
            for (int nt = 0; nt < 8; ++nt)
#pragma unroll
                for (int r = 0; r < 4; ++r)
                    if (mk4[r]) atomicAdd(&m_i[er[r] * 128 + nt * 16 + n15],
                                          nz(eij[m][r] * mv[m][nt][r]));
        }
    }
}

// ---------------------------------------------------------------------------
extern "C" void kernel_launch(void* const* d_in, const int* in_sizes, int n_in,
                              void* d_out, int out_size, void* d_ws, size_t ws_size,
                              hipStream_t stream) {
    const void* h = d_in[0];
    const void* x = d_in[1];
    const void* eattr = d_in[2];
    const void* v_init = d_in[3];
    const int* eidx = (const int*)d_in[4];

    const int N = in_sizes[0] / 128;
    const int E = in_sizes[4] / 2;
    const int* erow = eidx;
    const int* ecol = eidx + E;

    char* ws = (char*)d_ws;
    int* flag = (int*)ws;                       // 256
    short* W1t = (short*)(ws + 256);            // 73728
    short* W2t = (short*)(ws + 73984);          // 32768
    short* cW1t = (short*)(ws + 106752);        // 32768
    short* iW1t = (short*)(ws + 139520);        // 16384
    float* biasblk = (float*)(ws + 155904);     // 1412 floats -> pad to 162048
    short* nW1b = (short*)(ws + 162048);        // 65536
    short* nW2b = (short*)(ws + 227584);        // 32768
    short* vW1b = (short*)(ws + 260352);        // 32768
    int* bsum = (int*)(ws + 293120);            // 512
    int* bpre = (int*)(ws + 293632);            // 512
    short* hb = (short*)(ws + 294144);          // N*256
    size_t o = 294144 + (size_t)N * 256;
    // zero region: cnt + cur + agg_x + m_i (contiguous)
    size_t oZero = o;
    int* cnt = (int*)(ws + o); o += (size_t)N * 4;
    int* cur = (int*)(ws + o); o += (size_t)N * 4;
    float* agg_x = (float*)(ws + o); o += (size_t)N * 12;
    float* m_i = (float*)(ws + o); o += (size_t)N * 512;
    size_t zeroBytes = o - oZero;
    // CSR extras
    int* offp = (int*)(ws + o); o += (size_t)(N + 16) * 4;
    int* elist = (int*)(ws + o); o += (size_t)E * 4;
    const size_t need_csr = o;
    // precomputed h@W1 partials (bf16 N x 128 each)
    short* hA = (short*)(ws + o); o += (size_t)N * 256;
    short* hB = (short*)(ws + o); o += (size_t)N * 256;
    const size_t need_full = o;

    const bool csr = (ws_size >= need_csr);
    const bool pre = (ws_size >= need_full);

    detect_kernel<<<1, 64, 0, stream>>>((const unsigned int*)h, flag);

    const int prep_elems = 36864 + 16384 + 16384 + 8192 + 1412 + 32768 + 16384 + 16384;
    prep_kernel<<<(prep_elems + 255) / 256, 256, 0, stream>>>(
        d_in[5], d_in[7], d_in[9], d_in[12],
        d_in[6], d_in[8], d_in[10], d_in[11], d_in[13], d_in[14], d_in[15],
        d_in[17], d_in[19], d_in[21], d_in[22],
        d_in[16], d_in[18], d_in[20],
        W1t, W2t, cW1t, iW1t, biasblk, nW1b, nW2b, vW1b, flag);

    convh_kernel<<<(N * 128 + 255) / 256, 256, 0, stream>>>(h, hb, flag, N * 128);

    if (pre) {
        hw1_kernel<<<(N + 127) / 128, 256, 0, stream>>>(hb, W1t, hA, hB, N);
    }

    hipMemsetAsync((void*)(ws + oZero), 0, zeroBytes, stream);
    count_kernel<<<(E + 255) / 256, 256, 0, stream>>>(erow, cnt, E);

    if (csr) {
        const int nb = (N + 1023) / 1024;
        scan1_kernel<<<nb, 1024, 0, stream>>>(cnt, offp, bsum, N);
        scan2_kernel<<<1, 64, 0, stream>>>(bsum, bpre, nb);
        scan3_kernel<<<(N + 255) / 256, 256, 0, stream>>>(offp, bpre, N);
        fill_kernel<<<(E + 255) / 256, 256, 0, stream>>>(erow, offp, cur, elist, E);
    }

    if (pre && csr) {
        edge_kernel<true><<<(E + 63) / 64, 256, 0, stream>>>(
            hA, hB, x, eattr, erow, ecol, elist, W2t, cW1t, iW1t, biasblk,
            m_i, agg_x, E, flag);
    } else if (csr) {
        edge_kernel_old<true><<<(E + 127) / 128, 256, 0, stream>>>(
            hb, x, eattr, erow, ecol, elist, W1t, W2t, cW1t, iW1t, biasblk,
            m_i, agg_x, E, flag);
    } else {
        edge_kernel_old<false><<<(E + 127) / 128, 256, 0, stream>>>(
            hb, x, eattr, erow, ecol, nullptr, W1t, W2t, cW1t, iW1t, biasblk,
            m_i, agg_x, E, flag);
    }

    node_kernel<<<(N + 63) / 64, 256, 0, stream>>>(
        hb, x, v_init, cnt, m_i, agg_x,
        nW1b, nW2b, vW1b, biasblk, d_out, N, N * 128, N * 131,
        1.0f / (float)(N - 1), flag);
}